// Round 5
// baseline (2150.131 us; speedup 1.0000x reference)
//
#include <hip/hip_runtime.h>
#include <hip/hip_bf16.h>
#include <stdint.h>

constexpr int TK   = 4096;   // B*S tokens
constexpr int DIMC = 1024;
constexpr int DFFC = 4096;
constexpr int VOC  = 32000;
constexpr int NL   = 3;

typedef __attribute__((ext_vector_type(8))) short bf16x8;
typedef __attribute__((ext_vector_type(8))) _Float16 half8;
typedef __attribute__((ext_vector_type(4))) float f32x4;
using u16 = unsigned short;

__device__ __forceinline__ u16 f2bf(float f) {
  unsigned int u = __float_as_uint(f);
  u += 0x7FFF + ((u >> 16) & 1);           // RNE; inputs finite
  return (u16)(u >> 16);
}

__device__ __forceinline__ void split16(float v, u16& hi, u16& lo) {
  _Float16 a = (_Float16)v;
  _Float16 b = (_Float16)(v - (float)a);
  hi = __builtin_bit_cast(u16, a);
  lo = __builtin_bit_cast(u16, b);
}

__device__ __forceinline__ float gelu_f(float x) {
  float x3 = x * x * x;
  return 0.5f * x * (1.0f + tanhf(0.7978845608028654f * (x + 0.044715f * x3)));
}

// async global->LDS, 16B/lane; LDS dest = wave-uniform base (+lane*16 in HW)
__device__ __forceinline__ void gll16(const void* g, void* l) {
  __builtin_amdgcn_global_load_lds(
      (const __attribute__((address_space(1))) unsigned int*)g,
      (__attribute__((address_space(3))) unsigned int*)l, 16, 0, 0);
}

// ---------------- init ----------------
__global__ __launch_bounds__(256) void k_init(const int* __restrict__ x,
    const float* __restrict__ emb, float* __restrict__ h,
    int* __restrict__ surv, int* __restrict__ cnts) {
  const int t = blockIdx.x, tid = threadIdx.x;
  if (t == 0 && tid < 16) cnts[tid] = (tid == 12) ? TK : 0;
  if (tid == 0) surv[t] = t;
  const int tok = x[t];
  ((float4*)(h + (size_t)t * DIMC))[tid] =
      ((const float4*)(emb + (size_t)tok * DIMC))[tid];
}

// ---------------- layernorm -> 2 fp16 planes (x16 scale) ----------------
__global__ __launch_bounds__(256) void k_ln(const float* __restrict__ h,
    const int* __restrict__ surv, const int* __restrict__ pM,
    const float* __restrict__ g, const float* __restrict__ b,
    u16* __restrict__ hn1, u16* __restrict__ hn2) {
  const int bidx = blockIdx.x;
  if (bidx >= *pM) return;
  const int t = surv[bidx];
  const int tid = threadIdx.x;
  const int lane = tid & 63, wid = tid >> 6;
  __shared__ float sm[4];
  float4 v = ((const float4*)(h + (size_t)t * DIMC))[tid];
  float s = v.x + v.y + v.z + v.w;
#pragma unroll
  for (int o = 32; o; o >>= 1) s += __shfl_down(s, o);
  if (lane == 0) sm[wid] = s;
  __syncthreads();
  const float mean = (sm[0] + sm[1] + sm[2] + sm[3]) * (1.0f / DIMC);
  __syncthreads();
  float4 d;
  d.x = v.x - mean; d.y = v.y - mean; d.z = v.z - mean; d.w = v.w - mean;
  float q = d.x * d.x + d.y * d.y + d.z * d.z + d.w * d.w;
#pragma unroll
  for (int o = 32; o; o >>= 1) q += __shfl_down(q, o);
  if (lane == 0) sm[wid] = q;
  __syncthreads();
  const float var = (sm[0] + sm[1] + sm[2] + sm[3]) * (1.0f / DIMC);
  const float rstd = 1.0f / sqrtf(var + 1e-5f);
  float4 gg = ((const float4*)g)[tid];
  float4 bb = ((const float4*)b)[tid];
  float o4[4];
  o4[0] = (d.x * rstd * gg.x + bb.x) * 16.f;
  o4[1] = (d.y * rstd * gg.y + bb.y) * 16.f;
  o4[2] = (d.z * rstd * gg.z + bb.z) * 16.f;
  o4[3] = (d.w * rstd * gg.w + bb.w) * 16.f;
  ushort4 u1, u2;
  split16(o4[0], u1.x, u2.x); split16(o4[1], u1.y, u2.y);
  split16(o4[2], u1.z, u2.z); split16(o4[3], u1.w, u2.w);
  ((ushort4*)(hn1 + (size_t)bidx * DIMC))[tid] = u1;
  ((ushort4*)(hn2 + (size_t)bidx * DIMC))[tid] = u2;
}

// ---------------- weight transpose + fp16 2-split (x256 scale) ----------------
__global__ __launch_bounds__(256) void k_splitw(const float* __restrict__ W,
    int K, int N, u16* __restrict__ O1, u16* __restrict__ O2) {
  __shared__ float t[32][33];
  const int bk = blockIdx.x * 32, bn = blockIdx.y * 32;
  const int lx = threadIdx.x & 31, ly = threadIdx.x >> 5;
#pragma unroll
  for (int i = 0; i < 32; i += 8)
    t[ly + i][lx] = W[(size_t)(bk + ly + i) * N + bn + lx];
  __syncthreads();
#pragma unroll
  for (int i = 0; i < 32; i += 8) {
    float v = t[lx][ly + i] * 256.f;
    u16 h1, h2; split16(v, h1, h2);
    const size_t o = (size_t)(bn + ly + i) * K + bk + lx;
    O1[o] = h1; O2[o] = h2;
  }
}

// ---------------- f32 -> bf16 bulk convert (Wout, once per call) ----------------
__global__ __launch_bounds__(256) void k_cvtb(const float* __restrict__ in,
    u16* __restrict__ o, int n4) {
  int i = blockIdx.x * blockDim.x + threadIdx.x;
  const int stride = gridDim.x * blockDim.x;
  for (; i < n4; i += stride) {
    float4 v = ((const float4*)in)[i];
    ushort4 u;
    u.x = f2bf(v.x); u.y = f2bf(v.y); u.z = f2bf(v.z); u.w = f2bf(v.w);
    ((ushort4*)o)[i] = u;
  }
}

// ============ 2-phase prefetch MLP GEMM: C ~= (A1+A2)(B1+B2)^T (3-term) ============
// 128x128 tile, 4 waves (64x64 each), BK=32, fragment-linear LDS (conflict-free),
// double-buffered 64KB, STAGE(kt+1) issued before compute(kt).
// EPI==0: O1,O2 = split64(gelu(C*osc + bias))    EPI==1: PO[z-slab] = C*osc
template<int EPI>
__global__ __launch_bounds__(256, 2) void k_mlp(
    const u16* __restrict__ wsb,
    int offA, int pstrA, int lda,
    int offB, int pstrB, int ldb,
    int Kpart, const int* __restrict__ pM,
    const float* __restrict__ bias,
    u16* __restrict__ O1, u16* __restrict__ O2, int No,
    float* __restrict__ PO, float osc,
    int NRB, int NCB)
{
  const int nwg = gridDim.x;
  const int id = blockIdx.x;
  const int swz = (id & 7) * (nwg >> 3) + (id >> 3);   // XCD-chunked, bijective (nwg%8==0)
  const int cb = swz % NCB;
  const int r2 = swz / NCB;
  const int rb = r2 % NRB;
  const int z  = r2 / NRB;
  const int M = *pM;
  if (rb * 128 >= M) return;
  const int n0 = cb * 128;
  const int kz = z * Kpart;

  __shared__ u16 S[2][16384];     // [A1|A2|B1|B2] x 8 blocks of 512 u16 each; 64 KB
  const int tid = threadIdx.x, w = tid >> 6, l = tid & 63;
  const int lr16 = l & 15, hi = l >> 4, lh8 = hi * 8;

  // staging map: 32 blocks of 1KB; wave w owns blocks w*8..w*8+7
  int goff[8], loff[8];
#pragma unroll
  for (int q = 0; q < 8; ++q) {
    const int bi = w * 8 + q;
    if (bi < 16) {
      const int pp = bi >> 3, j = bi & 7;
      goff[q] = offA + pp * pstrA + (rb * 128 + j * 16 + lr16) * lda + lh8;
      loff[q] = pp * 4096 + j * 512;
    } else {
      const int bb = bi - 16, pp = bb >> 3, j = bb & 7;
      goff[q] = offB + pp * pstrB + (n0 + j * 16 + lr16) * ldb + lh8;
      loff[q] = 8192 + pp * 4096 + j * 512;
    }
  }

  const int wr = w >> 1, wc = w & 1;
  const int rdA = wr * 4 * 512 + l * 8;         // plane0; plane1 at +4096
  const int rdB = 8192 + wc * 4 * 512 + l * 8;

  f32x4 acc[4][4];
#pragma unroll
  for (int mi = 0; mi < 4; ++mi)
#pragma unroll
    for (int ni = 0; ni < 4; ++ni) acc[mi][ni] = (f32x4){0.f, 0.f, 0.f, 0.f};

  const int NT = Kpart / 32;
  auto STAGE = [&](int buf, int kt) {
#pragma unroll
    for (int q = 0; q < 8; ++q)
      gll16(wsb + (size_t)(goff[q] + kz + kt * 32), (void*)&S[buf][loff[q]]);
  };

  STAGE(0, 0);
  __syncthreads();                 // drains vmcnt(0): buf0 ready
  for (int kt = 0; kt < NT; ++kt) {
    const int cur = kt & 1;
    if (kt + 1 < NT) STAGE(cur ^ 1, kt + 1);   // loads fly under compute
    half8 a1[4], a2[4], b1[4], b2[4];
#pragma unroll
    for (int mi = 0; mi < 4; ++mi) {
      a1[mi] = *(const half8*)&S[cur][rdA + mi * 512];
      a2[mi] = *(const half8*)&S[cur][rdA + 4096 + mi * 512];
    }
#pragma unroll
    for (int ni = 0; ni < 4; ++ni) {
      b1[ni] = *(const half8*)&S[cur][rdB + ni * 512];
      b2[ni] = *(const half8*)&S[cur][rdB + 4096 + ni * 512];
    }
    __builtin_amdgcn_s_setprio(1);
#pragma unroll
    for (int mi = 0; mi < 4; ++mi)
#pragma unroll
      for (int ni = 0; ni < 4; ++ni) {
        acc[mi][ni] = __builtin_amdgcn_mfma_f32_16x16x32_f16(a2[mi], b1[ni], acc[mi][ni], 0, 0, 0);
        acc[mi][ni] = __builtin_amdgcn_mfma_f32_16x16x32_f16(a1[mi], b2[ni], acc[mi][ni], 0, 0, 0);
        acc[mi][ni] = __builtin_amdgcn_mfma_f32_16x16x32_f16(a1[mi], b1[ni], acc[mi][ni], 0, 0, 0);
      }
    __builtin_amdgcn_s_setprio(0);
    __syncthreads();               // waits vmcnt(0): next buf staged; cur reads done
  }

#pragma unroll
  for (int mi = 0; mi < 4; ++mi)
#pragma unroll
    for (int ni = 0; ni < 4; ++ni) {
      const int n = n0 + wc * 64 + ni * 16 + lr16;
#pragma unroll
      for (int r = 0; r < 4; ++r) {
        const int m = rb * 128 + wr * 64 + mi * 16 + hi * 4 + r;
        float v = acc[mi][ni][r] * osc;
        if constexpr (EPI == 0) {
          v = gelu_f(v + bias[n]) * 64.f;
          u16 h1, h2; split16(v, h1, h2);
          O1[(size_t)m * No + n] = h1;
          O2[(size_t)m * No + n] = h2;
        } else {
          PO[(size_t)(z * TK + m) * No + n] = v;
        }
      }
    }
}

// ============ 2-phase prefetch logits GEMM: bf16, 256x256 tile, 8 waves ============
__global__ __launch_bounds__(512, 2) void k_logits(
    const u16* __restrict__ wsb, int offA, int offB,
    const int* __restrict__ pcnt,
    const int* __restrict__ exit_idx,
    float* __restrict__ out)
{
  const int nwg = gridDim.x;                 // 2000
  const int id = blockIdx.x;
  const int swz = (id & 7) * (nwg >> 3) + (id >> 3);
  const int cb = swz % 125;
  const int rb = swz / 125;
  const int cnt = *pcnt;
  if (rb * 256 >= cnt) return;
  const int n0 = cb * 256;

  __shared__ u16 S[2][16384];     // [A(16 blk) | B(16 blk)]; 64 KB
  const int tid = threadIdx.x, w = tid >> 6, l = tid & 63;
  const int lr16 = l & 15, hi = l >> 4, lh8 = hi * 8;

  int goff[4], loff[4];
#pragma unroll
  for (int q = 0; q < 4; ++q) {
    const int bi = w * 4 + q;
    if (bi < 16) {
      goff[q] = offA + (rb * 256 + bi * 16 + lr16) * DIMC + lh8;
      loff[q] = bi * 512;
    } else {
      const int j = bi - 16;
      goff[q] = offB + (n0 + j * 16 + lr16) * DIMC + lh8;
      loff[q] = 8192 + j * 512;
    }
  }

  const int wr = w >> 2, wc = w & 3;         // 2x4 wave grid, 128x64 wave tile
  const int rdA = wr * 8 * 512 + l * 8;
  const int rdB = 8192 + wc * 4 * 512 + l * 8;

  f32x4 acc[8][4];
#pragma unroll
  for (int mi = 0; mi < 8; ++mi)
#pragma unroll
    for (int ni = 0; ni < 4; ++ni) acc[mi][ni] = (f32x4){0.f, 0.f, 0.f, 0.f};

  auto STAGE = [&](int buf, int kt) {
#pragma unroll
    for (int q = 0; q < 4; ++q)
      gll16(wsb + (size_t)(goff[q] + kt * 32), (void*)&S[buf][loff[q]]);
  };

  STAGE(0, 0);
  __syncthreads();
  const int NT = DIMC / 32;                  // 32
  for (int kt = 0; kt < NT; ++kt) {
    const int cur = kt & 1;
    if (kt + 1 < NT) STAGE(cur ^ 1, kt + 1);
    bf16x8 aF[8], bF[4];
#pragma unroll
    for (int mi = 0; mi < 8; ++mi)
      aF[mi] = *(const bf16x8*)&S[cur][rdA + mi * 512];
#pragma unroll
    for (int ni = 0; ni < 4; ++ni)
      bF[ni] = *(const bf16x8*)&S[cur][rdB + ni * 512];
    __builtin_amdgcn_s_setprio(1);
#pragma unroll
    for (int mi = 0; mi < 8; ++mi)
#pragma unroll
      for (int ni = 0; ni < 4; ++ni)
        acc[mi][ni] = __builtin_amdgcn_mfma_f32_16x16x32_bf16(aF[mi], bF[ni], acc[mi][ni], 0, 0, 0);
    __builtin_amdgcn_s_setprio(0);
    __syncthreads();
  }

  const int mvalid = cnt - rb * 256;
#pragma unroll
  for (int mi = 0; mi < 8; ++mi)
#pragma unroll
    for (int r = 0; r < 4; ++r) {
      const int mrow = wr * 128 + mi * 16 + hi * 4 + r;
      if (mrow < mvalid) {
        const int tok = exit_idx[rb * 256 + mrow];
        float* orow = out + (size_t)tok * VOC + n0 + wc * 64 + lr16;
#pragma unroll
        for (int ni = 0; ni < 4; ++ni)
          orow[ni * 16] = acc[mi][ni][r];
      }
    }
}

// ---------------- decide: o = h + p0 + p1 + b2; cos; route token ----------------
__global__ __launch_bounds__(256) void k_decide(
    float* __restrict__ h, const float* __restrict__ p,
    const float* __restrict__ bias,
    const int* __restrict__ surv_in, int* __restrict__ surv_out,
    const int* __restrict__ pM, int* __restrict__ cnts,
    int* __restrict__ exit_idx, u16* __restrict__ hexit,
    int stage)
{
  const int bidx = blockIdx.x;
  if (bidx >= *pM) return;
  const int t = surv_in[bidx];
  const int tid = threadIdx.x;
  const int lane = tid & 63, wid = tid >> 6;
  __shared__ float sm[12];
  __shared__ int sif[2];
  float4 a  = ((const float4*)(h + (size_t)t * DIMC))[tid];
  float4 p0 = ((const float4*)(p + (size_t)bidx * DIMC))[tid];
  float4 p1 = ((const float4*)(p + (size_t)(TK + bidx) * DIMC))[tid];
  float4 bb = ((const float4*)bias)[tid];
  float4 o;
  o.x = a.x + p0.x + p1.x + bb.x;
  o.y = a.y + p0.y + p1.y + bb.y;
  o.z = a.z + p0.z + p1.z + bb.z;
  o.w = a.w + p0.w + p1.w + bb.w;
  float hh = a.x * a.x + a.y * a.y + a.z * a.z + a.w * a.w;
  float ho = a.x * o.x + a.y * o.y + a.z * o.z + a.w * o.w;
  float oo = o.x * o.x + o.y * o.y + o.z * o.z + o.w * o.w;
#pragma unroll
  for (int off = 32; off; off >>= 1) {
    hh += __shfl_down(hh, off);
    ho += __shfl_down(ho, off);
    oo += __shfl_down(oo, off);
  }
  if (lane == 0) { sm[wid] = hh; sm[4 + wid] = ho; sm[8 + wid] = oo; }
  __syncthreads();
  if (tid == 0) {
    int take;
    if (stage == NL - 1) take = 1;
    else {
      const float HH = sm[0] + sm[1] + sm[2] + sm[3];
      const float HO = sm[4] + sm[5] + sm[6] + sm[7];
      const float OO = sm[8] + sm[9] + sm[10] + sm[11];
      const float cosv = HO / (sqrtf(HH) * sqrtf(OO) + 1e-8f);
      take = (cosv >= 0.98f) ? 1 : 0;
    }
    int pos;
    if (take) {
      pos = atomicAdd(&cnts[stage], 1);
      exit_idx[pos] = t;
    } else {
      pos = atomicAdd(&cnts[4 + stage], 1);
      surv_out[pos] = t;
    }
    sif[0] = take; sif[1] = pos;
  }
  __syncthreads();
  if (sif[0]) {
    u16* dst = hexit + (size_t)sif[1] * DIMC;
    ushort4 u;
    u.x = f2bf(o.x); u.y = f2bf(o.y); u.z = f2bf(o.z); u.w = f2bf(o.w);
    ((ushort4*)dst)[tid] = u;
  } else {
    ((float4*)(h + (size_t)t * DIMC))[tid] = o;
  }
}

// ---------------- host ----------------
extern "C" void kernel_launch(void* const* d_in, const int* in_sizes, int n_in,
                              void* d_out, int out_size, void* d_ws, size_t ws_size,
                              hipStream_t stream)
{
  const int*   x    = (const int*)d_in[0];
  const float* emb  = (const float*)d_in[1];
  const float* ln_g = (const float*)d_in[2];
  const float* ln_b = (const float*)d_in[3];
  const float* W1   = (const float*)d_in[4];
  const float* b1   = (const float*)d_in[5];
  const float* W2   = (const float*)d_in[6];
  const float* b2   = (const float*)d_in[7];
  const float* Wout = (const float*)d_in[8];
  float* out = (float*)d_out;

  char* p = (char*)d_ws;
  size_t off = 0;
  auto alloc = [&](size_t bytes) -> void* {
    void* r = p + off;
    off += (bytes + 255) & ~(size_t)255;
    return r;
  };
  u16* wsb = (u16*)d_ws;
  float* h    = (float*)alloc((size_t)TK * DIMC * 4);
  float* pbuf = (float*)alloc((size_t)2 * TK * DIMC * 4);   // gemm2 partials; hn planes alias
  u16* hn1 = (u16*)pbuf;
  u16* hn2 = hn1 + (size_t)TK * DIMC;
  u16* act1 = (u16*)alloc((size_t)2 * TK * DFFC * 2);       // act1 | act2 contiguous
  u16* act2 = act1 + (size_t)TK * DFFC;
  u16* Woutb = (u16*)alloc((size_t)VOC * DIMC * 2);
  u16* W1t = (u16*)alloc((size_t)2 * DFFC * DIMC * 2);
  u16* W2t = (u16*)alloc((size_t)2 * DIMC * DFFC * 2);
  u16* hexit = (u16*)alloc((size_t)TK * DIMC * 2);
  int* exit_idx = (int*)alloc((size_t)TK * 4);
  int* surv_a   = (int*)alloc((size_t)TK * 4);
  int* surv_b   = (int*)alloc((size_t)TK * 4);
  int* cnts     = (int*)alloc(64 * 4);
  // cnts[0..2]=exit counts; cnts[4..6]=survivor counts; cnts[12]=TK

  const int offHn  = (int)(hn1  - wsb);
  const int offAct = (int)(act1 - wsb);
  const int offWob = (int)(Woutb- wsb);
  const int offW1t = (int)(W1t  - wsb);
  const int offW2t = (int)(W2t  - wsb);
  const int offHex = (int)(hexit- wsb);

  k_init<<<TK, 256, 0, stream>>>(x, emb, h, surv_a, cnts);
  k_cvtb<<<2048, 256, 0, stream>>>(Wout, Woutb, VOC * DIMC / 4);
  int* surv_in  = surv_a;
  int* surv_out = surv_b;
  for (int i = 0; i < NL; ++i) {
    const int* pM = (i == 0) ? (cnts + 12) : (cnts + 4 + (i - 1));
    k_ln<<<TK, 256, 0, stream>>>(h, surv_in, pM, ln_g + i * DIMC, ln_b + i * DIMC, hn1, hn2);
    k_splitw<<<dim3(DIMC / 32, DFFC / 32), 256, 0, stream>>>(
        W1 + (size_t)i * DIMC * DFFC, DIMC, DFFC, W1t, W1t + (size_t)DFFC * DIMC);
    // gemm1: M x DFFC, K=DIMC.  grid 32 rb x 32 cb = 1024
    k_mlp<0><<<1024, 256, 0, stream>>>(
        wsb, offHn, TK * DIMC, DIMC, offW1t, DFFC * DIMC, DIMC,
        DIMC, pM, b1 + (size_t)i * DFFC, act1, act2, DFFC,
        nullptr, 1.f / 4096.f, 32, 32);
    k_splitw<<<dim3(DFFC / 32, DIMC / 32), 256, 0, stream>>>(
        W2 + (size_t)i * DFFC * DIMC, DFFC, DIMC, W2t, W2t + (size_t)DIMC * DFFC);
    // gemm2: M x DIMC, K=DFFC split-K2.  grid 32 rb x 8 cb x 2 z = 512
    k_mlp<1><<<512, 256, 0, stream>>>(
        wsb, offAct, TK * DFFC, DFFC, offW2t, DIMC * DFFC, DFFC,
        DFFC / 2, pM, nullptr, nullptr, nullptr, DIMC,
        pbuf, 1.f / 16384.f, 32, 8);
    k_decide<<<TK, 256, 0, stream>>>(h, pbuf, b2 + (size_t)i * DIMC,
        surv_in, surv_out, pM, cnts, exit_idx, hexit, i);
    // logits: 16 rb x 125 cb = 2000
    k_logits<<<2000, 512, 0, stream>>>(wsb, offHex, offWob, cnts + i, exit_idx, out);
    int* tmp = surv_in; surv_in = surv_out; surv_out = tmp;
  }
}

// Round 6
// 1937.357 us; speedup vs baseline: 1.1098x; 1.1098x over previous
//
#include <hip/hip_runtime.h>
#include <hip/hip_bf16.h>
#include <stdint.h>

constexpr int TK   = 4096;   // B*S tokens
constexpr int DIMC = 1024;
constexpr int DFFC = 4096;
constexpr int VOC  = 32000;
constexpr int NL   = 3;

typedef __attribute__((ext_vector_type(8))) short bf16x8;
typedef __attribute__((ext_vector_type(8))) _Float16 half8;
typedef __attribute__((ext_vector_type(4))) float f32x4;
using u16 = unsigned short;

__device__ __forceinline__ u16 f2bf(float f) {
  unsigned int u = __float_as_uint(f);
  u += 0x7FFF + ((u >> 16) & 1);           // RNE; inputs finite
  return (u16)(u >> 16);
}

__device__ __forceinline__ void split16(float v, u16& hi, u16& lo) {
  _Float16 a = (_Float16)v;
  _Float16 b = (_Float16)(v - (float)a);
  hi = __builtin_bit_cast(u16, a);
  lo = __builtin_bit_cast(u16, b);
}

__device__ __forceinline__ float gelu_f(float x) {
  float x3 = x * x * x;
  return 0.5f * x * (1.0f + tanhf(0.7978845608028654f * (x + 0.044715f * x3)));
}

// async global->LDS, 16B/lane; LDS dest = wave-uniform base (+lane*16 in HW)
__device__ __forceinline__ void gll16(const void* g, void* l) {
  __builtin_amdgcn_global_load_lds(
      (const __attribute__((address_space(1))) unsigned int*)g,
      (__attribute__((address_space(3))) unsigned int*)l, 16, 0, 0);
}

// ---------------- init ----------------
__global__ __launch_bounds__(256) void k_init(const int* __restrict__ x,
    const float* __restrict__ emb, float* __restrict__ h,
    int* __restrict__ surv, int* __restrict__ cnts) {
  const int t = blockIdx.x, tid = threadIdx.x;
  if (t == 0 && tid < 16) cnts[tid] = (tid == 12) ? TK : 0;
  if (tid == 0) surv[t] = t;
  const int tok = x[t];
  ((float4*)(h + (size_t)t * DIMC))[tid] =
      ((const float4*)(emb + (size_t)tok * DIMC))[tid];
}

// ---------------- layernorm -> 2 fp16 planes (x16 scale) ----------------
__global__ __launch_bounds__(256) void k_ln(const float* __restrict__ h,
    const int* __restrict__ surv, const int* __restrict__ pM,
    const float* __restrict__ g, const float* __restrict__ b,
    u16* __restrict__ hn1, u16* __restrict__ hn2) {
  const int bidx = blockIdx.x;
  if (bidx >= *pM) return;
  const int t = surv[bidx];
  const int tid = threadIdx.x;
  const int lane = tid & 63, wid = tid >> 6;
  __shared__ float sm[4];
  float4 v = ((const float4*)(h + (size_t)t * DIMC))[tid];
  float s = v.x + v.y + v.z + v.w;
#pragma unroll
  for (int o = 32; o; o >>= 1) s += __shfl_down(s, o);
  if (lane == 0) sm[wid] = s;
  __syncthreads();
  const float mean = (sm[0] + sm[1] + sm[2] + sm[3]) * (1.0f / DIMC);
  __syncthreads();
  float4 d;
  d.x = v.x - mean; d.y = v.y - mean; d.z = v.z - mean; d.w = v.w - mean;
  float q = d.x * d.x + d.y * d.y + d.z * d.z + d.w * d.w;
#pragma unroll
  for (int o = 32; o; o >>= 1) q += __shfl_down(q, o);
  if (lane == 0) sm[wid] = q;
  __syncthreads();
  const float var = (sm[0] + sm[1] + sm[2] + sm[3]) * (1.0f / DIMC);
  const float rstd = 1.0f / sqrtf(var + 1e-5f);
  float4 gg = ((const float4*)g)[tid];
  float4 bb = ((const float4*)b)[tid];
  float o4[4];
  o4[0] = (d.x * rstd * gg.x + bb.x) * 16.f;
  o4[1] = (d.y * rstd * gg.y + bb.y) * 16.f;
  o4[2] = (d.z * rstd * gg.z + bb.z) * 16.f;
  o4[3] = (d.w * rstd * gg.w + bb.w) * 16.f;
  ushort4 u1, u2;
  split16(o4[0], u1.x, u2.x); split16(o4[1], u1.y, u2.y);
  split16(o4[2], u1.z, u2.z); split16(o4[3], u1.w, u2.w);
  ((ushort4*)(hn1 + (size_t)bidx * DIMC))[tid] = u1;
  ((ushort4*)(hn2 + (size_t)bidx * DIMC))[tid] = u2;
}

// ---------------- weight transpose + fp16 2-split (x256 scale) ----------------
__global__ __launch_bounds__(256) void k_splitw(const float* __restrict__ W,
    int K, int N, u16* __restrict__ O1, u16* __restrict__ O2) {
  __shared__ float t[32][33];
  const int bk = blockIdx.x * 32, bn = blockIdx.y * 32;
  const int lx = threadIdx.x & 31, ly = threadIdx.x >> 5;
#pragma unroll
  for (int i = 0; i < 32; i += 8)
    t[ly + i][lx] = W[(size_t)(bk + ly + i) * N + bn + lx];
  __syncthreads();
#pragma unroll
  for (int i = 0; i < 32; i += 8) {
    float v = t[lx][ly + i] * 256.f;
    u16 h1, h2; split16(v, h1, h2);
    const size_t o = (size_t)(bn + ly + i) * K + bk + lx;
    O1[o] = h1; O2[o] = h2;
  }
}

// ---------------- f32 -> bf16 bulk convert (Wout, once per call) ----------------
__global__ __launch_bounds__(256) void k_cvtb(const float* __restrict__ in,
    u16* __restrict__ o, int n4) {
  int i = blockIdx.x * blockDim.x + threadIdx.x;
  const int stride = gridDim.x * blockDim.x;
  for (; i < n4; i += stride) {
    float4 v = ((const float4*)in)[i];
    ushort4 u;
    u.x = f2bf(v.x); u.y = f2bf(v.y); u.z = f2bf(v.z); u.w = f2bf(v.w);
    ((ushort4*)o)[i] = u;
  }
}

// ============ gemm1: 256x256 tile, BK=32, dbuf 128KB, 8 waves (128x64 tiles) ============
// C ~= (A1+A2)(B1+B2)^T 3-term;  act = split64(gelu(C/4096 + b1))
__global__ __launch_bounds__(512, 2) void k_mlp1(
    const u16* __restrict__ wsb,
    int offA, int pstrA,            // hn planes [TK][DIMC]
    int offB, int pstrB,            // W1t planes [DFFC][DIMC]
    const int* __restrict__ pM,
    const float* __restrict__ bias,
    u16* __restrict__ O1, u16* __restrict__ O2)
{
  const int id = blockIdx.x;                    // nwg = 256
  const int swz = (id & 7) * 32 + (id >> 3);    // XCD-chunked, bijective
  const int rb = swz & 15, cb = swz >> 4;
  const int M = *pM;
  if (rb * 256 >= M) return;
  const int n0 = cb * 256;

  __shared__ u16 S[2][32768];     // 2 x 64KB: [A1(16)|A2(16)|B1(16)|B2(16)] x 512u16 blocks
  const int tid = threadIdx.x, w = tid >> 6, l = tid & 63;
  const int lr16 = l & 15, hi = l >> 4;

  // staging: block bi = w*8+q; lane l fetches row (l&15), k-chunk (l>>4) of a 16x32 block
  int goff[8];
#pragma unroll
  for (int q = 0; q < 8; ++q) {
    const int bi = w * 8 + q;
    const int side = bi >> 5;                   // 0=A, 1=B
    const int pl = (bi >> 4) & 1;
    const int j = bi & 15;
    const int row = (side ? n0 : rb * 256) + j * 16 + lr16;
    const int base = side ? (offB + pl * pstrB) : (offA + pl * pstrA);
    goff[q] = base + row * DIMC + hi * 8;
  }

  const int wr = w >> 2, wc = w & 3;            // 2M x 4N wave grid
  f32x4 acc[8][4];
#pragma unroll
  for (int mi = 0; mi < 8; ++mi)
#pragma unroll
    for (int ni = 0; ni < 4; ++ni) acc[mi][ni] = (f32x4){0.f, 0.f, 0.f, 0.f};

  auto STAGE = [&](int buf, int kt) {
#pragma unroll
    for (int q = 0; q < 8; ++q)
      gll16(wsb + (size_t)goff[q] + kt * 32, (void*)&S[buf][(w * 8 + q) * 512]);
  };

  STAGE(0, 0);
  __syncthreads();
  const int NT = DIMC / 32;                     // 32
  for (int kt = 0; kt < NT; ++kt) {
    const int cur = kt & 1;
    if (kt + 1 < NT) STAGE(cur ^ 1, kt + 1);
    half8 b1v[4], b2v[4];
#pragma unroll
    for (int ni = 0; ni < 4; ++ni) {
      const int off = (32 + wc * 4 + ni) * 512 + l * 8;
      b1v[ni] = *(const half8*)&S[cur][off];
      b2v[ni] = *(const half8*)&S[cur][off + 8192];
    }
    __builtin_amdgcn_s_setprio(1);
#pragma unroll
    for (int mh = 0; mh < 2; ++mh) {
      half8 a1v[4], a2v[4];
#pragma unroll
      for (int i = 0; i < 4; ++i) {
        const int off = (wr * 8 + mh * 4 + i) * 512 + l * 8;
        a1v[i] = *(const half8*)&S[cur][off];
        a2v[i] = *(const half8*)&S[cur][off + 8192];
      }
#pragma unroll
      for (int i = 0; i < 4; ++i)
#pragma unroll
        for (int ni = 0; ni < 4; ++ni) {
          f32x4 c = acc[mh * 4 + i][ni];
          c = __builtin_amdgcn_mfma_f32_16x16x32_f16(a2v[i], b1v[ni], c, 0, 0, 0);
          c = __builtin_amdgcn_mfma_f32_16x16x32_f16(a1v[i], b2v[ni], c, 0, 0, 0);
          c = __builtin_amdgcn_mfma_f32_16x16x32_f16(a1v[i], b1v[ni], c, 0, 0, 0);
          acc[mh * 4 + i][ni] = c;
        }
    }
    __builtin_amdgcn_s_setprio(0);
    __syncthreads();
  }

#pragma unroll
  for (int mi = 0; mi < 8; ++mi)
#pragma unroll
    for (int ni = 0; ni < 4; ++ni) {
      const int n = n0 + wc * 64 + ni * 16 + lr16;
#pragma unroll
      for (int r = 0; r < 4; ++r) {
        const int m = rb * 256 + wr * 128 + mi * 16 + hi * 4 + r;
        float v = gelu_f(acc[mi][ni][r] * (1.f / 4096.f) + bias[n]) * 64.f;
        u16 h1, h2; split16(v, h1, h2);
        O1[(size_t)m * DFFC + n] = h1;
        O2[(size_t)m * DFFC + n] = h2;
      }
    }
}

// ============ gemm2: 256x128 tile, split-K2, BK=32, dbuf 96KB, 8 waves (64x64) ============
// PO[z-slab] = C/16384
__global__ __launch_bounds__(512, 2) void k_mlp2(
    const u16* __restrict__ wsb,
    int offA, int pstrA,            // act planes [TK][DFFC]
    int offB, int pstrB,            // W2t planes [DIMC][DFFC]
    const int* __restrict__ pM,
    float* __restrict__ PO)
{
  const int id = blockIdx.x;                    // nwg = 256
  const int swz = (id & 7) * 32 + (id >> 3);
  const int rb = swz & 15;
  const int rest = swz >> 4;                    // [0,16)
  const int cb = rest & 7, z = rest >> 3;
  const int M = *pM;
  if (rb * 256 >= M) return;
  const int n0 = cb * 128;
  const int kz = z * 2048;

  __shared__ u16 S[2][24576];     // 2 x 48KB: [A1(16)|A2(16)|B1(8)|B2(8)] x 512u16
  const int tid = threadIdx.x, w = tid >> 6, l = tid & 63;
  const int lr16 = l & 15, hi = l >> 4;

  int goff[6];
#pragma unroll
  for (int q = 0; q < 6; ++q) {
    const int bi = w * 6 + q;
    int base, row;
    if (bi < 32) {
      const int pl = bi >> 4, j = bi & 15;
      base = offA + pl * pstrA;
      row = rb * 256 + j * 16 + lr16;
    } else {
      const int bb = bi - 32, pl = bb >> 3, j = bb & 7;
      base = offB + pl * pstrB;
      row = n0 + j * 16 + lr16;
    }
    goff[q] = base + row * DFFC + kz + hi * 8;
  }

  const int wr = w >> 1, wc = w & 1;            // 4M x 2N wave grid
  f32x4 acc[4][4];
#pragma unroll
  for (int mi = 0; mi < 4; ++mi)
#pragma unroll
    for (int ni = 0; ni < 4; ++ni) acc[mi][ni] = (f32x4){0.f, 0.f, 0.f, 0.f};

  auto STAGE = [&](int buf, int kt) {
#pragma unroll
    for (int q = 0; q < 6; ++q)
      gll16(wsb + (size_t)goff[q] + kt * 32, (void*)&S[buf][(w * 6 + q) * 512]);
  };

  STAGE(0, 0);
  __syncthreads();
  const int NT = 2048 / 32;                     // 64
  for (int kt = 0; kt < NT; ++kt) {
    const int cur = kt & 1;
    if (kt + 1 < NT) STAGE(cur ^ 1, kt + 1);
    half8 a1v[4], a2v[4], b1v[4], b2v[4];
#pragma unroll
    for (int mi = 0; mi < 4; ++mi) {
      const int off = (wr * 4 + mi) * 512 + l * 8;
      a1v[mi] = *(const half8*)&S[cur][off];
      a2v[mi] = *(const half8*)&S[cur][off + 8192];
    }
#pragma unroll
    for (int ni = 0; ni < 4; ++ni) {
      const int off = (32 + wc * 4 + ni) * 512 + l * 8;
      b1v[ni] = *(const half8*)&S[cur][off];
      b2v[ni] = *(const half8*)&S[cur][off + 4096];
    }
    __builtin_amdgcn_s_setprio(1);
#pragma unroll
    for (int mi = 0; mi < 4; ++mi)
#pragma unroll
      for (int ni = 0; ni < 4; ++ni) {
        f32x4 c = acc[mi][ni];
        c = __builtin_amdgcn_mfma_f32_16x16x32_f16(a2v[mi], b1v[ni], c, 0, 0, 0);
        c = __builtin_amdgcn_mfma_f32_16x16x32_f16(a1v[mi], b2v[ni], c, 0, 0, 0);
        c = __builtin_amdgcn_mfma_f32_16x16x32_f16(a1v[mi], b1v[ni], c, 0, 0, 0);
        acc[mi][ni] = c;
      }
    __builtin_amdgcn_s_setprio(0);
    __syncthreads();
  }

#pragma unroll
  for (int mi = 0; mi < 4; ++mi)
#pragma unroll
    for (int ni = 0; ni < 4; ++ni) {
      const int n = n0 + wc * 64 + ni * 16 + lr16;
#pragma unroll
      for (int r = 0; r < 4; ++r) {
        const int m = rb * 256 + wr * 64 + mi * 16 + hi * 4 + r;
        PO[(size_t)(z * TK + m) * DIMC + n] = acc[mi][ni][r] * (1.f / 16384.f);
      }
    }
}

// ---------------- decide: o = h + p0 + p1 + b2; cos; route token ----------------
__global__ __launch_bounds__(256) void k_decide(
    float* __restrict__ h, const float* __restrict__ p,
    const float* __restrict__ bias,
    const int* __restrict__ surv_in, int* __restrict__ surv_out,
    const int* __restrict__ pM, int* __restrict__ cnts,
    int* __restrict__ exit_idx, u16* __restrict__ hexit,
    int stage)
{
  const int bidx = blockIdx.x;
  if (bidx >= *pM) return;
  const int t = surv_in[bidx];
  const int tid = threadIdx.x;
  const int lane = tid & 63, wid = tid >> 6;
  __shared__ float sm[12];
  __shared__ int sif[2];
  float4 a  = ((const float4*)(h + (size_t)t * DIMC))[tid];
  float4 p0 = ((const float4*)(p + (size_t)bidx * DIMC))[tid];
  float4 p1 = ((const float4*)(p + (size_t)(TK + bidx) * DIMC))[tid];
  float4 bb = ((const float4*)bias)[tid];
  float4 o;
  o.x = a.x + p0.x + p1.x + bb.x;
  o.y = a.y + p0.y + p1.y + bb.y;
  o.z = a.z + p0.z + p1.z + bb.z;
  o.w = a.w + p0.w + p1.w + bb.w;
  float hh = a.x * a.x + a.y * a.y + a.z * a.z + a.w * a.w;
  float ho = a.x * o.x + a.y * o.y + a.z * o.z + a.w * o.w;
  float oo = o.x * o.x + o.y * o.y + o.z * o.z + o.w * o.w;
#pragma unroll
  for (int off = 32; off; off >>= 1) {
    hh += __shfl_down(hh, off);
    ho += __shfl_down(ho, off);
    oo += __shfl_down(oo, off);
  }
  if (lane == 0) { sm[wid] = hh; sm[4 + wid] = ho; sm[8 + wid] = oo; }
  __syncthreads();
  if (tid == 0) {
    int take;
    if (stage == NL - 1) take = 1;
    else {
      const float HH = sm[0] + sm[1] + sm[2] + sm[3];
      const float HO = sm[4] + sm[5] + sm[6] + sm[7];
      const float OO = sm[8] + sm[9] + sm[10] + sm[11];
      const float cosv = HO / (sqrtf(HH) * sqrtf(OO) + 1e-8f);
      take = (cosv >= 0.98f) ? 1 : 0;
    }
    int pos;
    if (take) {
      pos = atomicAdd(&cnts[stage], 1);
      exit_idx[pos] = t;
    } else {
      pos = atomicAdd(&cnts[4 + stage], 1);
      surv_out[pos] = t;
    }
    sif[0] = take; sif[1] = pos;
  }
  __syncthreads();
  if (sif[0]) {
    u16* dst = hexit + (size_t)sif[1] * DIMC;
    ushort4 u;
    u.x = f2bf(o.x); u.y = f2bf(o.y); u.z = f2bf(o.z); u.w = f2bf(o.w);
    ((ushort4*)dst)[tid] = u;
  } else {
    ((float4*)(h + (size_t)t * DIMC))[tid] = o;
  }
}

// ============ logits: bf16, 256x256 tile, BK=32, dbuf 64KB, 8 waves ============
__global__ __launch_bounds__(512, 2) void k_logits(
    const u16* __restrict__ wsb, int offA, int offB,
    const int* __restrict__ pcnt,
    const int* __restrict__ exit_idx,
    float* __restrict__ out)
{
  const int nwg = gridDim.x;                 // 2000
  const int id = blockIdx.x;
  const int swz = (id & 7) * (nwg >> 3) + (id >> 3);
  const int cb = swz % 125;
  const int rb = swz / 125;
  const int cnt = *pcnt;
  if (rb * 256 >= cnt) return;
  const int n0 = cb * 256;

  __shared__ u16 S[2][16384];     // [A(16 blk) | B(16 blk)]; 64 KB
  const int tid = threadIdx.x, w = tid >> 6, l = tid & 63;
  const int lr16 = l & 15, hi = l >> 4, lh8 = hi * 8;

  int goff[4], loff[4];
#pragma unroll
  for (int q = 0; q < 4; ++q) {
    const int bi = w * 4 + q;
    if (bi < 16) {
      goff[q] = offA + (rb * 256 + bi * 16 + lr16) * DIMC + lh8;
      loff[q] = bi * 512;
    } else {
      const int j = bi - 16;
      goff[q] = offB + (n0 + j * 16 + lr16) * DIMC + lh8;
      loff[q] = 8192 + j * 512;
    }
  }

  const int wr = w >> 2, wc = w & 3;         // 2x4 wave grid, 128x64 wave tile
  const int rdA = wr * 8 * 512 + l * 8;
  const int rdB = 8192 + wc * 4 * 512 + l * 8;

  f32x4 acc[8][4];
#pragma unroll
  for (int mi = 0; mi < 8; ++mi)
#pragma unroll
    for (int ni = 0; ni < 4; ++ni) acc[mi][ni] = (f32x4){0.f, 0.f, 0.f, 0.f};

  auto STAGE = [&](int buf, int kt) {
#pragma unroll
    for (int q = 0; q < 4; ++q)
      gll16(wsb + (size_t)(goff[q] + kt * 32), (void*)&S[buf][loff[q]]);
  };

  STAGE(0, 0);
  __syncthreads();
  const int NT = DIMC / 32;                  // 32
  for (int kt = 0; kt < NT; ++kt) {
    const int cur = kt & 1;
    if (kt + 1 < NT) STAGE(cur ^ 1, kt + 1);
    bf16x8 aF[8], bF[4];
#pragma unroll
    for (int mi = 0; mi < 8; ++mi)
      aF[mi] = *(const bf16x8*)&S[cur][rdA + mi * 512];
#pragma unroll
    for (int ni = 0; ni < 4; ++ni)
      bF[ni] = *(const bf16x8*)&S[cur][rdB + ni * 512];
    __builtin_amdgcn_s_setprio(1);
#pragma unroll
    for (int mi = 0; mi < 8; ++mi)
#pragma unroll
      for (int ni = 0; ni < 4; ++ni)
        acc[mi][ni] = __builtin_amdgcn_mfma_f32_16x16x32_bf16(aF[mi], bF[ni], acc[mi][ni], 0, 0, 0);
    __builtin_amdgcn_s_setprio(0);
    __syncthreads();
  }

  const int mvalid = cnt - rb * 256;
#pragma unroll
  for (int mi = 0; mi < 8; ++mi)
#pragma unroll
    for (int r = 0; r < 4; ++r) {
      const int mrow = wr * 128 + mi * 16 + hi * 4 + r;
      if (mrow < mvalid) {
        const int tok = exit_idx[rb * 256 + mrow];
        float* orow = out + (size_t)tok * VOC + n0 + wc * 64 + lr16;
#pragma unroll
        for (int ni = 0; ni < 4; ++ni)
          orow[ni * 16] = acc[mi][ni][r];
      }
    }
}

// ---------------- host ----------------
extern "C" void kernel_launch(void* const* d_in, const int* in_sizes, int n_in,
                              void* d_out, int out_size, void* d_ws, size_t ws_size,
                              hipStream_t stream)
{
  const int*   x    = (const int*)d_in[0];
  const float* emb  = (const float*)d_in[1];
  const float* ln_g = (const float*)d_in[2];
  const float* ln_b = (const float*)d_in[3];
  const float* W1   = (const float*)d_in[4];
  const float* b1   = (const float*)d_in[5];
  const float* W2   = (const float*)d_in[6];
  const float* b2   = (const float*)d_in[7];
  const float* Wout = (const float*)d_in[8];
  float* out = (float*)d_out;

  char* p = (char*)d_ws;
  size_t off = 0;
  auto alloc = [&](size_t bytes) -> void* {
    void* r = p + off;
    off += (bytes + 255) & ~(size_t)255;
    return r;
  };
  u16* wsb = (u16*)d_ws;
  float* h    = (float*)alloc((size_t)TK * DIMC * 4);
  float* pbuf = (float*)alloc((size_t)2 * TK * DIMC * 4);   // gemm2 partials; hn planes alias
  u16* hn1 = (u16*)pbuf;
  u16* hn2 = hn1 + (size_t)TK * DIMC;
  u16* act1 = (u16*)alloc((size_t)2 * TK * DFFC * 2);       // act1 | act2 contiguous
  u16* act2 = act1 + (size_t)TK * DFFC;
  u16* Woutb = (u16*)alloc((size_t)VOC * DIMC * 2);
  u16* Wt = (u16*)alloc((size_t)2 * DFFC * DIMC * 2);       // shared by W1t / W2t (sequential)
  u16* hexit = (u16*)alloc((size_t)TK * DIMC * 2);
  int* exit_idx = (int*)alloc((size_t)TK * 4);
  int* surv_a   = (int*)alloc((size_t)TK * 4);
  int* surv_b   = (int*)alloc((size_t)TK * 4);
  int* cnts     = (int*)alloc(64 * 4);
  // cnts[0..2]=exit counts; cnts[4..6]=survivor counts; cnts[12]=TK

  const int offHn  = (int)(hn1  - wsb);
  const int offAct = (int)(act1 - wsb);
  const int offWob = (int)(Woutb- wsb);
  const int offWt  = (int)(Wt   - wsb);
  const int offHex = (int)(hexit- wsb);
  const int pstrHn  = TK * DIMC;
  const int pstrAct = TK * DFFC;
  const int pstrW   = DFFC * DIMC;

  k_init<<<TK, 256, 0, stream>>>(x, emb, h, surv_a, cnts);
  k_cvtb<<<2048, 256, 0, stream>>>(Wout, Woutb, VOC * DIMC / 4);
  int* surv_in  = surv_a;
  int* surv_out = surv_b;
  for (int i = 0; i < NL; ++i) {
    const int* pM = (i == 0) ? (cnts + 12) : (cnts + 4 + (i - 1));
    k_ln<<<TK, 256, 0, stream>>>(h, surv_in, pM, ln_g + i * DIMC, ln_b + i * DIMC, hn1, hn2);
    k_splitw<<<dim3(DIMC / 32, DFFC / 32), 256, 0, stream>>>(
        W1 + (size_t)i * DIMC * DFFC, DIMC, DFFC, Wt, Wt + (size_t)DFFC * DIMC);
    k_mlp1<<<256, 512, 0, stream>>>(
        wsb, offHn, pstrHn, offWt, pstrW, pM, b1 + (size_t)i * DFFC, act1, act2);
    k_splitw<<<dim3(DFFC / 32, DIMC / 32), 256, 0, stream>>>(
        W2 + (size_t)i * DFFC * DIMC, DFFC, DIMC, Wt, Wt + (size_t)DIMC * DFFC);
    k_mlp2<<<256, 512, 0, stream>>>(
        wsb, offAct, pstrAct, offWt, pstrW, pM, pbuf);
    k_decide<<<TK, 256, 0, stream>>>(h, pbuf, b2 + (size_t)i * DIMC,
        surv_in, surv_out, pM, cnts, exit_idx, hexit, i);
    k_logits<<<2000, 512, 0, stream>>>(wsb, offHex, offWob, cnts + i, exit_idx, out);
    int* tmp = surv_in; surv_in = surv_out; surv_out = tmp;
  }
}

// Round 8
// 1825.440 us; speedup vs baseline: 1.1779x; 1.0613x over previous
//
#include <hip/hip_runtime.h>
#include <hip/hip_bf16.h>
#include <stdint.h>

constexpr int TK   = 4096;   // B*S tokens
constexpr int DIMC = 1024;
constexpr int DFFC = 4096;
constexpr int VOC  = 32000;
constexpr int NL   = 3;

typedef __attribute__((ext_vector_type(8))) short bf16x8;
typedef __attribute__((ext_vector_type(8))) _Float16 half8;
typedef __attribute__((ext_vector_type(4))) float f32x4;
using u16 = unsigned short;

__device__ __forceinline__ u16 f2bf(float f) {
  unsigned int u = __float_as_uint(f);
  u += 0x7FFF + ((u >> 16) & 1);           // RNE; inputs finite
  return (u16)(u >> 16);
}

__device__ __forceinline__ void split16(float v, u16& hi, u16& lo) {
  _Float16 a = (_Float16)v;
  _Float16 b = (_Float16)(v - (float)a);
  hi = __builtin_bit_cast(u16, a);
  lo = __builtin_bit_cast(u16, b);
}

__device__ __forceinline__ float gelu_f(float x) {
  float x3 = x * x * x;
  return 0.5f * x * (1.0f + tanhf(0.7978845608028654f * (x + 0.044715f * x3)));
}

// async global->LDS, 16B/lane; LDS dest = wave-uniform base (+lane*16 in HW)
__device__ __forceinline__ void gll16(const void* g, void* l) {
  __builtin_amdgcn_global_load_lds(
      (const __attribute__((address_space(1))) unsigned int*)g,
      (__attribute__((address_space(3))) unsigned int*)l, 16, 0, 0);
}

// counted waitcnt: N outstanding allowed; kt uniform so branch is wave-uniform
__device__ __forceinline__ void wait_vm(int nleft) {
  if (nleft > 0) {
    // nleft is compile-time-constant at each call site via template below
  }
}

// ---------------- init ----------------
__global__ __launch_bounds__(256) void k_init(const int* __restrict__ x,
    const float* __restrict__ emb, float* __restrict__ h,
    int* __restrict__ surv, int* __restrict__ cnts) {
  const int t = blockIdx.x, tid = threadIdx.x;
  if (t == 0 && tid < 16) cnts[tid] = (tid == 12) ? TK : 0;
  if (tid == 0) surv[t] = t;
  const int tok = x[t];
  ((float4*)(h + (size_t)t * DIMC))[tid] =
      ((const float4*)(emb + (size_t)tok * DIMC))[tid];
}

// ---------------- layernorm -> 2 fp16 planes (x16 scale) ----------------
__global__ __launch_bounds__(256) void k_ln(const float* __restrict__ h,
    const int* __restrict__ surv, const int* __restrict__ pM,
    const float* __restrict__ g, const float* __restrict__ b,
    u16* __restrict__ hn1, u16* __restrict__ hn2) {
  const int bidx = blockIdx.x;
  if (bidx >= *pM) return;
  const int t = surv[bidx];
  const int tid = threadIdx.x;
  const int lane = tid & 63, wid = tid >> 6;
  __shared__ float sm[4];
  float4 v = ((const float4*)(h + (size_t)t * DIMC))[tid];
  float s = v.x + v.y + v.z + v.w;
#pragma unroll
  for (int o = 32; o; o >>= 1) s += __shfl_down(s, o);
  if (lane == 0) sm[wid] = s;
  __syncthreads();
  const float mean = (sm[0] + sm[1] + sm[2] + sm[3]) * (1.0f / DIMC);
  __syncthreads();
  float4 d;
  d.x = v.x - mean; d.y = v.y - mean; d.z = v.z - mean; d.w = v.w - mean;
  float q = d.x * d.x + d.y * d.y + d.z * d.z + d.w * d.w;
#pragma unroll
  for (int o = 32; o; o >>= 1) q += __shfl_down(q, o);
  if (lane == 0) sm[wid] = q;
  __syncthreads();
  const float var = (sm[0] + sm[1] + sm[2] + sm[3]) * (1.0f / DIMC);
  const float rstd = 1.0f / sqrtf(var + 1e-5f);
  float4 gg = ((const float4*)g)[tid];
  float4 bb = ((const float4*)b)[tid];
  float o4[4];
  o4[0] = (d.x * rstd * gg.x + bb.x) * 16.f;
  o4[1] = (d.y * rstd * gg.y + bb.y) * 16.f;
  o4[2] = (d.z * rstd * gg.z + bb.z) * 16.f;
  o4[3] = (d.w * rstd * gg.w + bb.w) * 16.f;
  ushort4 u1, u2;
  split16(o4[0], u1.x, u2.x); split16(o4[1], u1.y, u2.y);
  split16(o4[2], u1.z, u2.z); split16(o4[3], u1.w, u2.w);
  ((ushort4*)(hn1 + (size_t)bidx * DIMC))[tid] = u1;
  ((ushort4*)(hn2 + (size_t)bidx * DIMC))[tid] = u2;
}

// ---------------- weight transpose + fp16 2-split (x256 scale) ----------------
__global__ __launch_bounds__(256) void k_splitw(const float* __restrict__ W,
    int K, int N, u16* __restrict__ O1, u16* __restrict__ O2) {
  __shared__ float t[32][33];
  const int bk = blockIdx.x * 32, bn = blockIdx.y * 32;
  const int lx = threadIdx.x & 31, ly = threadIdx.x >> 5;
#pragma unroll
  for (int i = 0; i < 32; i += 8)
    t[ly + i][lx] = W[(size_t)(bk + ly + i) * N + bn + lx];
  __syncthreads();
#pragma unroll
  for (int i = 0; i < 32; i += 8) {
    float v = t[lx][ly + i] * 256.f;
    u16 h1, h2; split16(v, h1, h2);
    const size_t o = (size_t)(bn + ly + i) * K + bk + lx;
    O1[o] = h1; O2[o] = h2;
  }
}

// ---------------- f32 -> bf16 bulk convert (Wout, once per call) ----------------
__global__ __launch_bounds__(256) void k_cvtb(const float* __restrict__ in,
    u16* __restrict__ o, int n4) {
  int i = blockIdx.x * blockDim.x + threadIdx.x;
  const int stride = gridDim.x * blockDim.x;
  for (; i < n4; i += stride) {
    float4 v = ((const float4*)in)[i];
    ushort4 u;
    u.x = f2bf(v.x); u.y = f2bf(v.y); u.z = f2bf(v.z); u.w = f2bf(v.w);
    ((ushort4*)o)[i] = u;
  }
}

// ============ gemm1: 256x256 tile, BK=32, dbuf 128KB, 8 waves (128x64 tiles) ============
// counted-vmcnt pipeline, 2-ahead; epilogue drains to 0 on the last tile.
// C ~= (A1+A2)(B1+B2)^T 3-term;  act = split64(gelu(C/4096 + b1))
__global__ __launch_bounds__(512, 1) void k_mlp1(
    const u16* __restrict__ wsb,
    int offA, int pstrA,            // hn planes [TK][DIMC]
    int offB, int pstrB,            // W1t planes [DFFC][DIMC]
    const int* __restrict__ pM,
    const float* __restrict__ bias,
    u16* __restrict__ O1, u16* __restrict__ O2)
{
  const int id = blockIdx.x;                    // nwg = 256
  const int swz = (id & 7) * 32 + (id >> 3);    // XCD-chunked, bijective
  const int rb = swz & 15, cb = swz >> 4;
  const int M = *pM;
  if (rb * 256 >= M) return;
  const int n0 = cb * 256;

  __shared__ u16 S[2][32768];     // 2 x 64KB: [A1(16)|A2(16)|B1(16)|B2(16)] x 512u16 blocks
  const int tid = threadIdx.x, w = tid >> 6, l = tid & 63;
  const int lr16 = l & 15, hi = l >> 4;

  int goff[8];
#pragma unroll
  for (int q = 0; q < 8; ++q) {
    const int bi = w * 8 + q;
    const int side = bi >> 5;                   // 0=A, 1=B
    const int pl = (bi >> 4) & 1;
    const int j = bi & 15;
    const int row = (side ? n0 : rb * 256) + j * 16 + lr16;
    const int base = side ? (offB + pl * pstrB) : (offA + pl * pstrA);
    goff[q] = base + row * DIMC + hi * 8;
  }

  const int wr = w >> 2, wc = w & 3;            // 2M x 4N wave grid
  f32x4 acc[8][4];
#pragma unroll
  for (int mi = 0; mi < 8; ++mi)
#pragma unroll
    for (int ni = 0; ni < 4; ++ni) acc[mi][ni] = (f32x4){0.f, 0.f, 0.f, 0.f};

  auto STAGE = [&](int buf, int kt) {
#pragma unroll
    for (int q = 0; q < 8; ++q)
      gll16(wsb + (size_t)goff[q] + kt * 32, (void*)&S[buf][(w * 8 + q) * 512]);
  };

  STAGE(0, 0);
  STAGE(1, 1);
  const int NT = DIMC / 32;                     // 32
  for (int kt = 0; kt < NT; ++kt) {
    const int cur = kt & 1;
    // STAGE(kt) must be complete; STAGE(kt+1) (if any) stays in flight.
    if (kt + 1 < NT) asm volatile("s_waitcnt vmcnt(8)" ::: "memory");
    else             asm volatile("s_waitcnt vmcnt(0)" ::: "memory");
    __builtin_amdgcn_s_barrier();
    half8 b1v[4], b2v[4];
#pragma unroll
    for (int ni = 0; ni < 4; ++ni) {
      const int off = (32 + wc * 4 + ni) * 512 + l * 8;
      b1v[ni] = *(const half8*)&S[cur][off];
      b2v[ni] = *(const half8*)&S[cur][off + 8192];
    }
    __builtin_amdgcn_s_setprio(1);
#pragma unroll
    for (int mh = 0; mh < 2; ++mh) {
      half8 a1v[4], a2v[4];
#pragma unroll
      for (int i = 0; i < 4; ++i) {
        const int off = (wr * 8 + mh * 4 + i) * 512 + l * 8;
        a1v[i] = *(const half8*)&S[cur][off];
        a2v[i] = *(const half8*)&S[cur][off + 8192];
      }
#pragma unroll
      for (int i = 0; i < 4; ++i)
#pragma unroll
        for (int ni = 0; ni < 4; ++ni) {
          f32x4 c = acc[mh * 4 + i][ni];
          c = __builtin_amdgcn_mfma_f32_16x16x32_f16(a2v[i], b1v[ni], c, 0, 0, 0);
          c = __builtin_amdgcn_mfma_f32_16x16x32_f16(a1v[i], b2v[ni], c, 0, 0, 0);
          c = __builtin_amdgcn_mfma_f32_16x16x32_f16(a1v[i], b1v[ni], c, 0, 0, 0);
          acc[mh * 4 + i][ni] = c;
        }
    }
    __builtin_amdgcn_s_setprio(0);
    asm volatile("s_waitcnt lgkmcnt(0)" ::: "memory"); // all ds_reads of buf[cur] done
    __builtin_amdgcn_s_barrier();
    if (kt + 2 < NT) STAGE(cur, kt + 2);               // refill 2-ahead
  }

#pragma unroll
  for (int mi = 0; mi < 8; ++mi)
#pragma unroll
    for (int ni = 0; ni < 4; ++ni) {
      const int n = n0 + wc * 64 + ni * 16 + lr16;
#pragma unroll
      for (int r = 0; r < 4; ++r) {
        const int m = rb * 256 + wr * 128 + mi * 16 + hi * 4 + r;
        float v = gelu_f(acc[mi][ni][r] * (1.f / 4096.f) + bias[n]) * 64.f;
        u16 h1, h2; split16(v, h1, h2);
        O1[(size_t)m * DFFC + n] = h1;
        O2[(size_t)m * DFFC + n] = h2;
      }
    }
}

// ============ gemm2: 256x128 tile, split-K2, BK=32, dbuf 96KB, 8 waves (64x64) ============
// counted-vmcnt pipeline; epilogue drain.  PO[z-slab] = C/16384
__global__ __launch_bounds__(512, 1) void k_mlp2(
    const u16* __restrict__ wsb,
    int offA, int pstrA,            // act planes [TK][DFFC]
    int offB, int pstrB,            // W2t planes [DIMC][DFFC]
    const int* __restrict__ pM,
    float* __restrict__ PO)
{
  const int id = blockIdx.x;                    // nwg = 256
  const int swz = (id & 7) * 32 + (id >> 3);
  const int rb = swz & 15;
  const int rest = swz >> 4;                    // [0,16)
  const int cb = rest & 7, z = rest >> 3;
  const int M = *pM;
  if (rb * 256 >= M) return;
  const int n0 = cb * 128;
  const int kz = z * 2048;

  __shared__ u16 S[2][24576];     // 2 x 48KB: [A1(16)|A2(16)|B1(8)|B2(8)] x 512u16
  const int tid = threadIdx.x, w = tid >> 6, l = tid & 63;
  const int lr16 = l & 15, hi = l >> 4;

  int goff[6];
#pragma unroll
  for (int q = 0; q < 6; ++q) {
    const int bi = w * 6 + q;
    int base, row;
    if (bi < 32) {
      const int pl = bi >> 4, j = bi & 15;
      base = offA + pl * pstrA;
      row = rb * 256 + j * 16 + lr16;
    } else {
      const int bb = bi - 32, pl = bb >> 3, j = bb & 7;
      base = offB + pl * pstrB;
      row = n0 + j * 16 + lr16;
    }
    goff[q] = base + row * DFFC + kz + hi * 8;
  }

  const int wr = w >> 1, wc = w & 1;            // 4M x 2N wave grid
  f32x4 acc[4][4];
#pragma unroll
  for (int mi = 0; mi < 4; ++mi)
#pragma unroll
    for (int ni = 0; ni < 4; ++ni) acc[mi][ni] = (f32x4){0.f, 0.f, 0.f, 0.f};

  auto STAGE = [&](int buf, int kt) {
#pragma unroll
    for (int q = 0; q < 6; ++q)
      gll16(wsb + (size_t)goff[q] + kt * 32, (void*)&S[buf][(w * 6 + q) * 512]);
  };

  STAGE(0, 0);
  STAGE(1, 1);
  const int NT = 2048 / 32;                     // 64
  for (int kt = 0; kt < NT; ++kt) {
    const int cur = kt & 1;
    if (kt + 1 < NT) asm volatile("s_waitcnt vmcnt(6)" ::: "memory");
    else             asm volatile("s_waitcnt vmcnt(0)" ::: "memory");
    __builtin_amdgcn_s_barrier();
    half8 a1v[4], a2v[4], b1v[4], b2v[4];
#pragma unroll
    for (int mi = 0; mi < 4; ++mi) {
      const int off = (wr * 4 + mi) * 512 + l * 8;
      a1v[mi] = *(const half8*)&S[cur][off];
      a2v[mi] = *(const half8*)&S[cur][off + 8192];
    }
#pragma unroll
    for (int ni = 0; ni < 4; ++ni) {
      const int off = (32 + wc * 4 + ni) * 512 + l * 8;
      b1v[ni] = *(const half8*)&S[cur][off];
      b2v[ni] = *(const half8*)&S[cur][off + 4096];
    }
    __builtin_amdgcn_s_setprio(1);
#pragma unroll
    for (int mi = 0; mi < 4; ++mi)
#pragma unroll
      for (int ni = 0; ni < 4; ++ni) {
        f32x4 c = acc[mi][ni];
        c = __builtin_amdgcn_mfma_f32_16x16x32_f16(a2v[mi], b1v[ni], c, 0, 0, 0);
        c = __builtin_amdgcn_mfma_f32_16x16x32_f16(a1v[mi], b2v[ni], c, 0, 0, 0);
        c = __builtin_amdgcn_mfma_f32_16x16x32_f16(a1v[mi], b1v[ni], c, 0, 0, 0);
        acc[mi][ni] = c;
      }
    __builtin_amdgcn_s_setprio(0);
    asm volatile("s_waitcnt lgkmcnt(0)" ::: "memory");
    __builtin_amdgcn_s_barrier();
    if (kt + 2 < NT) STAGE(cur, kt + 2);
  }

#pragma unroll
  for (int mi = 0; mi < 4; ++mi)
#pragma unroll
    for (int ni = 0; ni < 4; ++ni) {
      const int n = n0 + wc * 64 + ni * 16 + lr16;
#pragma unroll
      for (int r = 0; r < 4; ++r) {
        const int m = rb * 256 + wr * 64 + mi * 16 + hi * 4 + r;
        PO[(size_t)(z * TK + m) * DIMC + n] = acc[mi][ni][r] * (1.f / 16384.f);
      }
    }
}

// ---------------- decide: o = h + p0 + p1 + b2; cos; route token ----------------
__global__ __launch_bounds__(256) void k_decide(
    float* __restrict__ h, const float* __restrict__ p,
    const float* __restrict__ bias,
    const int* __restrict__ surv_in, int* __restrict__ surv_out,
    const int* __restrict__ pM, int* __restrict__ cnts,
    int* __restrict__ exit_idx, u16* __restrict__ hexit,
    int stage)
{
  const int bidx = blockIdx.x;
  if (bidx >= *pM) return;
  const int t = surv_in[bidx];
  const int tid = threadIdx.x;
  const int lane = tid & 63, wid = tid >> 6;
  __shared__ float sm[12];
  __shared__ int sif[2];
  float4 a  = ((const float4*)(h + (size_t)t * DIMC))[tid];
  float4 p0 = ((const float4*)(p + (size_t)bidx * DIMC))[tid];
  float4 p1 = ((const float4*)(p + (size_t)(TK + bidx) * DIMC))[tid];
  float4 bb = ((const float4*)bias)[tid];
  float4 o;
  o.x = a.x + p0.x + p1.x + bb.x;
  o.y = a.y + p0.y + p1.y + bb.y;
  o.z = a.z + p0.z + p1.z + bb.z;
  o.w = a.w + p0.w + p1.w + bb.w;
  float hh = a.x * a.x + a.y * a.y + a.z * a.z + a.w * a.w;
  float ho = a.x * o.x + a.y * o.y + a.z * o.z + a.w * o.w;
  float oo = o.x * o.x + o.y * o.y + o.z * o.z + o.w * o.w;
#pragma unroll
  for (int off = 32; off; off >>= 1) {
    hh += __shfl_down(hh, off);
    ho += __shfl_down(ho, off);
    oo += __shfl_down(oo, off);
  }
  if (lane == 0) { sm[wid] = hh; sm[4 + wid] = ho; sm[8 + wid] = oo; }
  __syncthreads();
  if (tid == 0) {
    int take;
    if (stage == NL - 1) take = 1;
    else {
      const float HH = sm[0] + sm[1] + sm[2] + sm[3];
      const float HO = sm[4] + sm[5] + sm[6] + sm[7];
      const float OO = sm[8] + sm[9] + sm[10] + sm[11];
      const float cosv = HO / (sqrtf(HH) * sqrtf(OO) + 1e-8f);
      take = (cosv >= 0.98f) ? 1 : 0;
    }
    int pos;
    if (take) {
      pos = atomicAdd(&cnts[stage], 1);
      exit_idx[pos] = t;
    } else {
      pos = atomicAdd(&cnts[4 + stage], 1);
      surv_out[pos] = t;
    }
    sif[0] = take; sif[1] = pos;
  }
  __syncthreads();
  if (sif[0]) {
    u16* dst = hexit + (size_t)sif[1] * DIMC;
    ushort4 u;
    u.x = f2bf(o.x); u.y = f2bf(o.y); u.z = f2bf(o.z); u.w = f2bf(o.w);
    ((ushort4*)dst)[tid] = u;
  } else {
    ((float4*)(h + (size_t)t * DIMC))[tid] = o;
  }
}

// ============ logits: bf16, 256x256 tile, BK=32, dbuf 64KB, 8 waves ============
// counted-vmcnt pipeline; epilogue drain.
__global__ __launch_bounds__(512, 2) void k_logits(
    const u16* __restrict__ wsb, int offA, int offB,
    const int* __restrict__ pcnt,
    const int* __restrict__ exit_idx,
    float* __restrict__ out)
{
  const int nwg = gridDim.x;                 // 2000
  const int id = blockIdx.x;
  const int swz = (id & 7) * (nwg >> 3) + (id >> 3);
  const int cb = swz % 125;
  const int rb = swz / 125;
  const int cnt = *pcnt;
  if (rb * 256 >= cnt) return;
  const int n0 = cb * 256;

  __shared__ u16 S[2][16384];     // [A(16 blk) | B(16 blk)]; 64 KB
  const int tid = threadIdx.x, w = tid >> 6, l = tid & 63;
  const int lr16 = l & 15, hi = l >> 4, lh8 = hi * 8;

  int goff[4], loff[4];
#pragma unroll
  for (int q = 0; q < 4; ++q) {
    const int bi = w * 4 + q;
    if (bi < 16) {
      goff[q] = offA + (rb * 256 + bi * 16 + lr16) * DIMC + lh8;
      loff[q] = bi * 512;
    } else {
      const int j = bi - 16;
      goff[q] = offB + (n0 + j * 16 + lr16) * DIMC + lh8;
      loff[q] = 8192 + j * 512;
    }
  }

  const int wr = w >> 2, wc = w & 3;         // 2x4 wave grid, 128x64 wave tile
  const int rdA = wr * 8 * 512 + l * 8;
  const int rdB = 8192 + wc * 4 * 512 + l * 8;

  f32x4 acc[8][4];
#pragma unroll
  for (int mi = 0; mi < 8; ++mi)
#pragma unroll
    for (int ni = 0; ni < 4; ++ni) acc[mi][ni] = (f32x4){0.f, 0.f, 0.f, 0.f};

  auto STAGE = [&](int buf, int kt) {
#pragma unroll
    for (int q = 0; q < 4; ++q)
      gll16(wsb + (size_t)(goff[q] + kt * 32), (void*)&S[buf][loff[q]]);
  };

  STAGE(0, 0);
  STAGE(1, 1);
  const int NT = DIMC / 32;                  // 32
  for (int kt = 0; kt < NT; ++kt) {
    const int cur = kt & 1;
    if (kt + 1 < NT) asm volatile("s_waitcnt vmcnt(4)" ::: "memory");
    else             asm volatile("s_waitcnt vmcnt(0)" ::: "memory");
    __builtin_amdgcn_s_barrier();
    bf16x8 aF[8], bF[4];
#pragma unroll
    for (int mi = 0; mi < 8; ++mi)
      aF[mi] = *(const bf16x8*)&S[cur][rdA + mi * 512];
#pragma unroll
    for (int ni = 0; ni < 4; ++ni)
      bF[ni] = *(const bf16x8*)&S[cur][rdB + ni * 512];
    __builtin_amdgcn_s_setprio(1);
#pragma unroll
    for (int mi = 0; mi < 8; ++mi)
#pragma unroll
      for (int ni = 0; ni < 4; ++ni)
        acc[mi][ni] = __builtin_amdgcn_mfma_f32_16x16x32_bf16(aF[mi], bF[ni], acc[mi][ni], 0, 0, 0);
    __builtin_amdgcn_s_setprio(0);
    asm volatile("s_waitcnt lgkmcnt(0)" ::: "memory");
    __builtin_amdgcn_s_barrier();
    if (kt + 2 < NT) STAGE(cur, kt + 2);
  }

  const int mvalid = cnt - rb * 256;
#pragma unroll
  for (int mi = 0; mi < 8; ++mi)
#pragma unroll
    for (int r = 0; r < 4; ++r) {
      const int mrow = wr * 128 + mi * 16 + hi * 4 + r;
      if (mrow < mvalid) {
        const int tok = exit_idx[rb * 256 + mrow];
        float* orow = out + (size_t)tok * VOC + n0 + wc * 64 + lr16;
#pragma unroll
        for (int ni = 0; ni < 4; ++ni)
          orow[ni * 16] = acc[mi][ni][r];
      }
    }
}

// ---------------- host ----------------
extern "C" void kernel_launch(void* const* d_in, const int* in_sizes, int n_in,
                              void* d_out, int out_size, void* d_ws, size_t ws_size,
                              hipStream_t stream)
{
  const int*   x    = (const int*)d_in[0];
  const float* emb  = (const float*)d_in[1];
  const float* ln_g = (const float*)d_in[2];
  const float* ln_b = (const float*)d_in[3];
  const float* W1   = (const float*)d_in[4];
  const float* b1   = (const float*)d_in[5];
  const float* W2   = (const float*)d_in[6];
  const float* b2   = (const float*)d_in[7];
  const float* Wout = (const float*)d_in[8];
  float* out = (float*)d_out;

  char* p = (char*)d_ws;
  size_t off = 0;
  auto alloc = [&](size_t bytes) -> void* {
    void* r = p + off;
    off += (bytes + 255) & ~(size_t)255;
    return r;
  };
  u16* wsb = (u16*)d_ws;
  float* h    = (float*)alloc((size_t)TK * DIMC * 4);
  float* pbuf = (float*)alloc((size_t)2 * TK * DIMC * 4);   // gemm2 partials; hn planes alias
  u16* hn1 = (u16*)pbuf;
  u16* hn2 = hn1 + (size_t)TK * DIMC;
  u16* act1 = (u16*)alloc((size_t)2 * TK * DFFC * 2);       // act1 | act2 contiguous
  u16* act2 = act1 + (size_t)TK * DFFC;
  u16* Woutb = (u16*)alloc((size_t)VOC * DIMC * 2);
  u16* Wt = (u16*)alloc((size_t)2 * DFFC * DIMC * 2);       // shared by W1t / W2t (sequential)
  u16* hexit = (u16*)alloc((size_t)TK * DIMC * 2);
  int* exit_idx = (int*)alloc((size_t)TK * 4);
  int* surv_a   = (int*)alloc((size_t)TK * 4);
  int* surv_b   = (int*)alloc((size_t)TK * 4);
  int* cnts     = (int*)alloc(64 * 4);
  // cnts[0..2]=exit counts; cnts[4..6]=survivor counts; cnts[12]=TK

  const int offHn  = (int)(hn1  - wsb);
  const int offAct = (int)(act1 - wsb);
  const int offWob = (int)(Woutb- wsb);
  const int offWt  = (int)(Wt   - wsb);
  const int offHex = (int)(hexit- wsb);
  const int pstrHn  = TK * DIMC;
  const int pstrAct = TK * DFFC;
  const int pstrW   = DFFC * DIMC;

  k_init<<<TK, 256, 0, stream>>>(x, emb, h, surv_a, cnts);
  k_cvtb<<<2048, 256, 0, stream>>>(Wout, Woutb, VOC * DIMC / 4);
  int* surv_in  = surv_a;
  int* surv_out = surv_b;
  for (int i = 0; i < NL; ++i) {
    const int* pM = (i == 0) ? (cnts + 12) : (cnts + 4 + (i - 1));
    k_ln<<<TK, 256, 0, stream>>>(h, surv_in, pM, ln_g + i * DIMC, ln_b + i * DIMC, hn1, hn2);
    k_splitw<<<dim3(DIMC / 32, DFFC / 32), 256, 0, stream>>>(
        W1 + (size_t)i * DIMC * DFFC, DIMC, DFFC, Wt, Wt + (size_t)DFFC * DIMC);
    k_mlp1<<<256, 512, 0, stream>>>(
        wsb, offHn, pstrHn, offWt, pstrW, pM, b1 + (size_t)i * DFFC, act1, act2);
    k_splitw<<<dim3(DFFC / 32, DIMC / 32), 256, 0, stream>>>(
        W2 + (size_t)i * DFFC * DIMC, DFFC, DIMC, Wt, Wt + (size_t)DIMC * DFFC);
    k_mlp2<<<256, 512, 0, stream>>>(
        wsb, offAct, pstrAct, offWt, pstrW, pM, pbuf);
    k_decide<<<TK, 256, 0, stream>>>(h, pbuf, b2 + (size_t)i * DIMC,
        surv_in, surv_out, pM, cnts, exit_idx, hexit, i);
    k_logits<<<2000, 512, 0, stream>>>(wsb, offHex, offWob, cnts + i, exit_idx, out);
    int* tmp = surv_in; surv_in = surv_out; surv_out = tmp;
  }
}

// Round 9
// 1799.448 us; speedup vs baseline: 1.1949x; 1.0144x over previous
//
#include <hip/hip_runtime.h>
#include <hip/hip_bf16.h>
#include <stdint.h>

constexpr int TK   = 4096;   // B*S tokens
constexpr int DIMC = 1024;
constexpr int DFFC = 4096;
constexpr int VOC  = 32000;
constexpr int NL   = 3;

typedef __attribute__((ext_vector_type(8))) short bf16x8;
typedef __attribute__((ext_vector_type(8))) _Float16 half8;
typedef __attribute__((ext_vector_type(4))) float f32x4;
using u16 = unsigned short;

__device__ __forceinline__ u16 f2bf(float f) {
  unsigned int u = __float_as_uint(f);
  u += 0x7FFF + ((u >> 16) & 1);           // RNE; inputs finite
  return (u16)(u >> 16);
}

__device__ __forceinline__ void split16(float v, u16& hi, u16& lo) {
  _Float16 a = (_Float16)v;
  _Float16 b = (_Float16)(v - (float)a);
  hi = __builtin_bit_cast(u16, a);
  lo = __builtin_bit_cast(u16, b);
}

__device__ __forceinline__ float gelu_f(float x) {
  float x3 = x * x * x;
  return 0.5f * x * (1.0f + tanhf(0.7978845608028654f * (x + 0.044715f * x3)));
}

// async global->LDS, 16B/lane; LDS dest = wave-uniform base (+lane*16 in HW)
__device__ __forceinline__ void gll16(const void* g, void* l) {
  __builtin_amdgcn_global_load_lds(
      (const __attribute__((address_space(1))) unsigned int*)g,
      (__attribute__((address_space(3))) unsigned int*)l, 16, 0, 0);
}

// ---------------- init ----------------
__global__ __launch_bounds__(256) void k_init(const int* __restrict__ x,
    const float* __restrict__ emb, float* __restrict__ h,
    int* __restrict__ surv, int* __restrict__ cnts) {
  const int t = blockIdx.x, tid = threadIdx.x;
  if (t == 0 && tid < 16) cnts[tid] = (tid == 12) ? TK : 0;
  if (tid == 0) surv[t] = t;
  const int tok = x[t];
  ((float4*)(h + (size_t)t * DIMC))[tid] =
      ((const float4*)(emb + (size_t)tok * DIMC))[tid];
}

// ---------------- layernorm -> 2 fp16 planes (x16 scale) ----------------
__global__ __launch_bounds__(256) void k_ln(const float* __restrict__ h,
    const int* __restrict__ surv, const int* __restrict__ pM,
    const float* __restrict__ g, const float* __restrict__ b,
    u16* __restrict__ hn1, u16* __restrict__ hn2) {
  const int bidx = blockIdx.x;
  if (bidx >= *pM) return;
  const int t = surv[bidx];
  const int tid = threadIdx.x;
  const int lane = tid & 63, wid = tid >> 6;
  __shared__ float sm[4];
  float4 v = ((const float4*)(h + (size_t)t * DIMC))[tid];
  float s = v.x + v.y + v.z + v.w;
#pragma unroll
  for (int o = 32; o; o >>= 1) s += __shfl_down(s, o);
  if (lane == 0) sm[wid] = s;
  __syncthreads();
  const float mean = (sm[0] + sm[1] + sm[2] + sm[3]) * (1.0f / DIMC);
  __syncthreads();
  float4 d;
  d.x = v.x - mean; d.y = v.y - mean; d.z = v.z - mean; d.w = v.w - mean;
  float q = d.x * d.x + d.y * d.y + d.z * d.z + d.w * d.w;
#pragma unroll
  for (int o = 32; o; o >>= 1) q += __shfl_down(q, o);
  if (lane == 0) sm[wid] = q;
  __syncthreads();
  const float var = (sm[0] + sm[1] + sm[2] + sm[3]) * (1.0f / DIMC);
  const float rstd = 1.0f / sqrtf(var + 1e-5f);
  float4 gg = ((const float4*)g)[tid];
  float4 bb = ((const float4*)b)[tid];
  float o4[4];
  o4[0] = (d.x * rstd * gg.x + bb.x) * 16.f;
  o4[1] = (d.y * rstd * gg.y + bb.y) * 16.f;
  o4[2] = (d.z * rstd * gg.z + bb.z) * 16.f;
  o4[3] = (d.w * rstd * gg.w + bb.w) * 16.f;
  ushort4 u1, u2;
  split16(o4[0], u1.x, u2.x); split16(o4[1], u1.y, u2.y);
  split16(o4[2], u1.z, u2.z); split16(o4[3], u1.w, u2.w);
  ((ushort4*)(hn1 + (size_t)bidx * DIMC))[tid] = u1;
  ((ushort4*)(hn2 + (size_t)bidx * DIMC))[tid] = u2;
}

// ---------------- weight transpose + fp16 2-split (x256 scale) ----------------
__global__ __launch_bounds__(256) void k_splitw(const float* __restrict__ W,
    int K, int N, u16* __restrict__ O1, u16* __restrict__ O2) {
  __shared__ float t[32][33];
  const int bk = blockIdx.x * 32, bn = blockIdx.y * 32;
  const int lx = threadIdx.x & 31, ly = threadIdx.x >> 5;
#pragma unroll
  for (int i = 0; i < 32; i += 8)
    t[ly + i][lx] = W[(size_t)(bk + ly + i) * N + bn + lx];
  __syncthreads();
#pragma unroll
  for (int i = 0; i < 32; i += 8) {
    float v = t[lx][ly + i] * 256.f;
    u16 h1, h2; split16(v, h1, h2);
    const size_t o = (size_t)(bn + ly + i) * K + bk + lx;
    O1[o] = h1; O2[o] = h2;
  }
}

// ---------------- f32 -> bf16 bulk convert (Wout, once per call) ----------------
__global__ __launch_bounds__(256) void k_cvtb(const float* __restrict__ in,
    u16* __restrict__ o, int n4) {
  int i = blockIdx.x * blockDim.x + threadIdx.x;
  const int stride = gridDim.x * blockDim.x;
  for (; i < n4; i += stride) {
    float4 v = ((const float4*)in)[i];
    ushort4 u;
    u.x = f2bf(v.x); u.y = f2bf(v.y); u.z = f2bf(v.z); u.w = f2bf(v.w);
    ((ushort4*)o)[i] = u;
  }
}

// ============ gemm1: 256x256 tile, BK=32, dbuf 128KB, 8 waves (128x64 tiles) ============
// 2-phase fine interleave + counted vmcnt.  C ~= (A1+A2)(B1+B2)^T 3-term;
// act = split64(gelu(C/4096 + b1))
__global__ __launch_bounds__(512, 1) void k_mlp1(
    const u16* __restrict__ wsb,
    int offA, int pstrA,            // hn planes [TK][DIMC]
    int offB, int pstrB,            // W1t planes [DFFC][DIMC]
    const int* __restrict__ pM,
    const float* __restrict__ bias,
    u16* __restrict__ O1, u16* __restrict__ O2)
{
  const int id = blockIdx.x;                    // nwg = 256
  const int swz = (id & 7) * 32 + (id >> 3);    // XCD-chunked, bijective
  const int rb = swz & 15, cb = swz >> 4;
  const int M = *pM;
  if (rb * 256 >= M) return;
  const int n0 = cb * 256;

  __shared__ u16 S[2][32768];     // 2 x 64KB: [A1(16)|A2(16)|B1(16)|B2(16)] x 512u16 blocks
  const int tid = threadIdx.x, w = tid >> 6, l = tid & 63;
  const int lr16 = l & 15, hi = l >> 4;

  int goff[8];
#pragma unroll
  for (int q = 0; q < 8; ++q) {
    const int bi = w * 8 + q;
    const int side = bi >> 5;                   // 0=A, 1=B
    const int pl = (bi >> 4) & 1;
    const int j = bi & 15;
    const int row = (side ? n0 : rb * 256) + j * 16 + lr16;
    const int base = side ? (offB + pl * pstrB) : (offA + pl * pstrA);
    goff[q] = base + row * DIMC + hi * 8;
  }

  const int wr = w >> 2, wc = w & 3;            // 2M x 4N wave grid
  f32x4 acc[8][4];
#pragma unroll
  for (int mi = 0; mi < 8; ++mi)
#pragma unroll
    for (int ni = 0; ni < 4; ++ni) acc[mi][ni] = (f32x4){0.f, 0.f, 0.f, 0.f};

  auto STAGE = [&](int buf, int kt) {
#pragma unroll
    for (int q = 0; q < 8; ++q)
      gll16(wsb + (size_t)goff[q] + kt * 32, (void*)&S[buf][(w * 8 + q) * 512]);
  };

  STAGE(0, 0);
  STAGE(1, 1);
  const int NT = DIMC / 32;                     // 32
  for (int kt = 0; kt < NT; ++kt) {
    const int cur = kt & 1;
    if (kt + 1 < NT) asm volatile("s_waitcnt vmcnt(8)" ::: "memory");
    else             asm volatile("s_waitcnt vmcnt(0)" ::: "memory");
    __builtin_amdgcn_s_barrier();
    // ---- phase 1: B all + A(mh=0); 24 MFMA
    half8 b1v[4], b2v[4], a1v[4], a2v[4];
#pragma unroll
    for (int ni = 0; ni < 4; ++ni) {
      const int off = (32 + wc * 4 + ni) * 512 + l * 8;
      b1v[ni] = *(const half8*)&S[cur][off];
      b2v[ni] = *(const half8*)&S[cur][off + 8192];
    }
#pragma unroll
    for (int i = 0; i < 4; ++i) {
      const int off = (wr * 8 + i) * 512 + l * 8;
      a1v[i] = *(const half8*)&S[cur][off];
      a2v[i] = *(const half8*)&S[cur][off + 8192];
    }
    asm volatile("s_waitcnt lgkmcnt(0)" ::: "memory");
    __builtin_amdgcn_s_setprio(1);
#pragma unroll
    for (int i = 0; i < 4; ++i)
#pragma unroll
      for (int ni = 0; ni < 4; ++ni) {
        f32x4 c = acc[i][ni];
        c = __builtin_amdgcn_mfma_f32_16x16x32_f16(a2v[i], b1v[ni], c, 0, 0, 0);
        c = __builtin_amdgcn_mfma_f32_16x16x32_f16(a1v[i], b2v[ni], c, 0, 0, 0);
        c = __builtin_amdgcn_mfma_f32_16x16x32_f16(a1v[i], b1v[ni], c, 0, 0, 0);
        acc[i][ni] = c;
      }
    __builtin_amdgcn_s_setprio(0);
    __builtin_amdgcn_s_barrier();
    // ---- phase 2: A(mh=1); 24 MFMA
#pragma unroll
    for (int i = 0; i < 4; ++i) {
      const int off = (wr * 8 + 4 + i) * 512 + l * 8;
      a1v[i] = *(const half8*)&S[cur][off];
      a2v[i] = *(const half8*)&S[cur][off + 8192];
    }
    asm volatile("s_waitcnt lgkmcnt(0)" ::: "memory");
    __builtin_amdgcn_s_setprio(1);
#pragma unroll
    for (int i = 0; i < 4; ++i)
#pragma unroll
      for (int ni = 0; ni < 4; ++ni) {
        f32x4 c = acc[4 + i][ni];
        c = __builtin_amdgcn_mfma_f32_16x16x32_f16(a2v[i], b1v[ni], c, 0, 0, 0);
        c = __builtin_amdgcn_mfma_f32_16x16x32_f16(a1v[i], b2v[ni], c, 0, 0, 0);
        c = __builtin_amdgcn_mfma_f32_16x16x32_f16(a1v[i], b1v[ni], c, 0, 0, 0);
        acc[4 + i][ni] = c;
      }
    __builtin_amdgcn_s_setprio(0);
    __builtin_amdgcn_s_barrier();               // all reads of buf[cur] done (data-dep)
    if (kt + 2 < NT) STAGE(cur, kt + 2);        // refill 2-ahead
  }

#pragma unroll
  for (int mi = 0; mi < 8; ++mi)
#pragma unroll
    for (int ni = 0; ni < 4; ++ni) {
      const int n = n0 + wc * 64 + ni * 16 + lr16;
#pragma unroll
      for (int r = 0; r < 4; ++r) {
        const int m = rb * 256 + wr * 128 + mi * 16 + hi * 4 + r;
        float v = gelu_f(acc[mi][ni][r] * (1.f / 4096.f) + bias[n]) * 64.f;
        u16 h1, h2; split16(v, h1, h2);
        O1[(size_t)m * DFFC + n] = h1;
        O2[(size_t)m * DFFC + n] = h2;
      }
    }
}

// ============ gemm2: 256x128 tile, split-K2, BK=32, dbuf 96KB, 8 waves (64x64) ============
// 2-phase fine interleave + counted vmcnt.  PO[z-slab] = C/16384
__global__ __launch_bounds__(512, 1) void k_mlp2(
    const u16* __restrict__ wsb,
    int offA, int pstrA,            // act planes [TK][DFFC]
    int offB, int pstrB,            // W2t planes [DIMC][DFFC]
    const int* __restrict__ pM,
    float* __restrict__ PO)
{
  const int id = blockIdx.x;                    // nwg = 256
  const int swz = (id & 7) * 32 + (id >> 3);
  const int rb = swz & 15;
  const int rest = swz >> 4;                    // [0,16)
  const int cb = rest & 7, z = rest >> 3;
  const int M = *pM;
  if (rb * 256 >= M) return;
  const int n0 = cb * 128;
  const int kz = z * 2048;

  __shared__ u16 S[2][24576];     // 2 x 48KB: [A1(16)|A2(16)|B1(8)|B2(8)] x 512u16
  const int tid = threadIdx.x, w = tid >> 6, l = tid & 63;
  const int lr16 = l & 15, hi = l >> 4;

  int goff[6];
#pragma unroll
  for (int q = 0; q < 6; ++q) {
    const int bi = w * 6 + q;
    int base, row;
    if (bi < 32) {
      const int pl = bi >> 4, j = bi & 15;
      base = offA + pl * pstrA;
      row = rb * 256 + j * 16 + lr16;
    } else {
      const int bb = bi - 32, pl = bb >> 3, j = bb & 7;
      base = offB + pl * pstrB;
      row = n0 + j * 16 + lr16;
    }
    goff[q] = base + row * DFFC + kz + hi * 8;
  }

  const int wr = w >> 1, wc = w & 1;            // 4M x 2N wave grid
  f32x4 acc[4][4];
#pragma unroll
  for (int mi = 0; mi < 4; ++mi)
#pragma unroll
    for (int ni = 0; ni < 4; ++ni) acc[mi][ni] = (f32x4){0.f, 0.f, 0.f, 0.f};

  auto STAGE = [&](int buf, int kt) {
#pragma unroll
    for (int q = 0; q < 6; ++q)
      gll16(wsb + (size_t)goff[q] + kt * 32, (void*)&S[buf][(w * 6 + q) * 512]);
  };

  STAGE(0, 0);
  STAGE(1, 1);
  const int NT = 2048 / 32;                     // 64
  for (int kt = 0; kt < NT; ++kt) {
    const int cur = kt & 1;
    if (kt + 1 < NT) asm volatile("s_waitcnt vmcnt(6)" ::: "memory");
    else             asm volatile("s_waitcnt vmcnt(0)" ::: "memory");
    __builtin_amdgcn_s_barrier();
    // ---- phase 1: A all + B(ni 0..1); 24 MFMA
    half8 a1v[4], a2v[4], b1v[2], b2v[2];
#pragma unroll
    for (int mi = 0; mi < 4; ++mi) {
      const int off = (wr * 4 + mi) * 512 + l * 8;
      a1v[mi] = *(const half8*)&S[cur][off];
      a2v[mi] = *(const half8*)&S[cur][off + 8192];
    }
#pragma unroll
    for (int ni = 0; ni < 2; ++ni) {
      const int off = (32 + wc * 4 + ni) * 512 + l * 8;
      b1v[ni] = *(const half8*)&S[cur][off];
      b2v[ni] = *(const half8*)&S[cur][off + 4096];
    }
    asm volatile("s_waitcnt lgkmcnt(0)" ::: "memory");
    __builtin_amdgcn_s_setprio(1);
#pragma unroll
    for (int mi = 0; mi < 4; ++mi)
#pragma unroll
      for (int ni = 0; ni < 2; ++ni) {
        f32x4 c = acc[mi][ni];
        c = __builtin_amdgcn_mfma_f32_16x16x32_f16(a2v[mi], b1v[ni], c, 0, 0, 0);
        c = __builtin_amdgcn_mfma_f32_16x16x32_f16(a1v[mi], b2v[ni], c, 0, 0, 0);
        c = __builtin_amdgcn_mfma_f32_16x16x32_f16(a1v[mi], b1v[ni], c, 0, 0, 0);
        acc[mi][ni] = c;
      }
    __builtin_amdgcn_s_setprio(0);
    __builtin_amdgcn_s_barrier();
    // ---- phase 2: B(ni 2..3); 24 MFMA
#pragma unroll
    for (int ni = 0; ni < 2; ++ni) {
      const int off = (32 + wc * 4 + 2 + ni) * 512 + l * 8;
      b1v[ni] = *(const half8*)&S[cur][off];
      b2v[ni] = *(const half8*)&S[cur][off + 4096];
    }
    asm volatile("s_waitcnt lgkmcnt(0)" ::: "memory");
    __builtin_amdgcn_s_setprio(1);
#pragma unroll
    for (int mi = 0; mi < 4; ++mi)
#pragma unroll
      for (int ni = 0; ni < 2; ++ni) {
        f32x4 c = acc[mi][2 + ni];
        c = __builtin_amdgcn_mfma_f32_16x16x32_f16(a2v[mi], b1v[ni], c, 0, 0, 0);
        c = __builtin_amdgcn_mfma_f32_16x16x32_f16(a1v[mi], b2v[ni], c, 0, 0, 0);
        c = __builtin_amdgcn_mfma_f32_16x16x32_f16(a1v[mi], b1v[ni], c, 0, 0, 0);
        acc[mi][2 + ni] = c;
      }
    __builtin_amdgcn_s_setprio(0);
    __builtin_amdgcn_s_barrier();
    if (kt + 2 < NT) STAGE(cur, kt + 2);
  }

#pragma unroll
  for (int mi = 0; mi < 4; ++mi)
#pragma unroll
    for (int ni = 0; ni < 4; ++ni) {
      const int n = n0 + wc * 64 + ni * 16 + lr16;
#pragma unroll
      for (int r = 0; r < 4; ++r) {
        const int m = rb * 256 + wr * 64 + mi * 16 + hi * 4 + r;
        PO[(size_t)(z * TK + m) * DIMC + n] = acc[mi][ni][r] * (1.f / 16384.f);
      }
    }
}

// ---------------- decide: o = h + p0 + p1 + b2; cos; route token ----------------
__global__ __launch_bounds__(256) void k_decide(
    float* __restrict__ h, const float* __restrict__ p,
    const float* __restrict__ bias,
    const int* __restrict__ surv_in, int* __restrict__ surv_out,
    const int* __restrict__ pM, int* __restrict__ cnts,
    int* __restrict__ exit_idx, u16* __restrict__ hexit,
    int stage)
{
  const int bidx = blockIdx.x;
  if (bidx >= *pM) return;
  const int t = surv_in[bidx];
  const int tid = threadIdx.x;
  const int lane = tid & 63, wid = tid >> 6;
  __shared__ float sm[12];
  __shared__ int sif[2];
  float4 a  = ((const float4*)(h + (size_t)t * DIMC))[tid];
  float4 p0 = ((const float4*)(p + (size_t)bidx * DIMC))[tid];
  float4 p1 = ((const float4*)(p + (size_t)(TK + bidx) * DIMC))[tid];
  float4 bb = ((const float4*)bias)[tid];
  float4 o;
  o.x = a.x + p0.x + p1.x + bb.x;
  o.y = a.y + p0.y + p1.y + bb.y;
  o.z = a.z + p0.z + p1.z + bb.z;
  o.w = a.w + p0.w + p1.w + bb.w;
  float hh = a.x * a.x + a.y * a.y + a.z * a.z + a.w * a.w;
  float ho = a.x * o.x + a.y * o.y + a.z * o.z + a.w * o.w;
  float oo = o.x * o.x + o.y * o.y + o.z * o.z + o.w * o.w;
#pragma unroll
  for (int off = 32; off; off >>= 1) {
    hh += __shfl_down(hh, off);
    ho += __shfl_down(ho, off);
    oo += __shfl_down(oo, off);
  }
  if (lane == 0) { sm[wid] = hh; sm[4 + wid] = ho; sm[8 + wid] = oo; }
  __syncthreads();
  if (tid == 0) {
    int take;
    if (stage == NL - 1) take = 1;
    else {
      const float HH = sm[0] + sm[1] + sm[2] + sm[3];
      const float HO = sm[4] + sm[5] + sm[6] + sm[7];
      const float OO = sm[8] + sm[9] + sm[10] + sm[11];
      const float cosv = HO / (sqrtf(HH) * sqrtf(OO) + 1e-8f);
      take = (cosv >= 0.98f) ? 1 : 0;
    }
    int pos;
    if (take) {
      pos = atomicAdd(&cnts[stage], 1);
      exit_idx[pos] = t;
    } else {
      pos = atomicAdd(&cnts[4 + stage], 1);
      surv_out[pos] = t;
    }
    sif[0] = take; sif[1] = pos;
  }
  __syncthreads();
  if (sif[0]) {
    u16* dst = hexit + (size_t)sif[1] * DIMC;
    ushort4 u;
    u.x = f2bf(o.x); u.y = f2bf(o.y); u.z = f2bf(o.z); u.w = f2bf(o.w);
    ((ushort4*)dst)[tid] = u;
  } else {
    ((float4*)(h + (size_t)t * DIMC))[tid] = o;
  }
}

// ============ logits: bf16, 256x256 tile, BK=32, 4-ring 128KB, 8 waves ============
// m201-style: 3 tiles prefetched, stages spread across 2 phases, counted vmcnt,
// nontemporal C stores (keep Woutb L3-resident).
__global__ __launch_bounds__(512, 1) void k_logits(
    const u16* __restrict__ wsb, int offA, int offB,
    const int* __restrict__ pcnt,
    const int* __restrict__ exit_idx,
    float* __restrict__ out)
{
  const int nwg = gridDim.x;                 // 2000
  const int id = blockIdx.x;
  const int swz = (id & 7) * (nwg >> 3) + (id >> 3);
  const int cb = swz % 125;
  const int rb = swz / 125;
  const int cnt = *pcnt;
  if (rb * 256 >= cnt) return;
  const int n0 = cb * 256;

  __shared__ u16 S[4][16384];     // 4-ring x 32KB: [A(16 blk) | B(16 blk)] x 512u16
  const int tid = threadIdx.x, w = tid >> 6, l = tid & 63;
  const int lr16 = l & 15, hi = l >> 4, lh8 = hi * 8;

  int goff[4], loff[4];
#pragma unroll
  for (int q = 0; q < 4; ++q) {
    const int bi = w * 4 + q;
    if (bi < 16) {
      goff[q] = offA + (rb * 256 + bi * 16 + lr16) * DIMC + lh8;
      loff[q] = bi * 512;
    } else {
      const int j = bi - 16;
      goff[q] = offB + (n0 + j * 16 + lr16) * DIMC + lh8;
      loff[q] = 8192 + j * 512;
    }
  }

  const int wr = w >> 2, wc = w & 3;         // 2x4 wave grid, 128x64 wave tile
  const int rdA = wr * 8 * 512 + l * 8;
  const int rdB = 8192 + wc * 4 * 512 + l * 8;

  f32x4 acc[8][4];
#pragma unroll
  for (int mi = 0; mi < 8; ++mi)
#pragma unroll
    for (int ni = 0; ni < 4; ++ni) acc[mi][ni] = (f32x4){0.f, 0.f, 0.f, 0.f};

  auto STAGE_H = [&](int kt, int h) {        // half-stage: 2 gll16 into ring slot kt&3
#pragma unroll
    for (int q = h * 2; q < h * 2 + 2; ++q)
      gll16(wsb + (size_t)(goff[q] + kt * 32), (void*)&S[kt & 3][loff[q]]);
  };

  STAGE_H(0, 0); STAGE_H(0, 1);
  STAGE_H(1, 0); STAGE_H(1, 1);
  STAGE_H(2, 0); STAGE_H(2, 1);              // 12 loads/wave in flight
  const int NT = DIMC / 32;                  // 32
  for (int kt = 0; kt < NT; ++kt) {
    const int cur = kt & 3;
    if (kt < NT - 2)      asm volatile("s_waitcnt vmcnt(8)" ::: "memory");
    else if (kt < NT - 1) asm volatile("s_waitcnt vmcnt(4)" ::: "memory");
    else                  asm volatile("s_waitcnt vmcnt(0)" ::: "memory");
    __builtin_amdgcn_s_barrier();
    // ---- phase 1: B + A(0..3); stage half0 of kt+3; 16 MFMA
    bf16x8 bF[4], aF[4];
#pragma unroll
    for (int ni = 0; ni < 4; ++ni)
      bF[ni] = *(const bf16x8*)&S[cur][rdB + ni * 512];
#pragma unroll
    for (int mi = 0; mi < 4; ++mi)
      aF[mi] = *(const bf16x8*)&S[cur][rdA + mi * 512];
    if (kt + 3 < NT) STAGE_H(kt + 3, 0);     // target ring slot read-complete since iter kt-1
    asm volatile("s_waitcnt lgkmcnt(0)" ::: "memory");
    __builtin_amdgcn_s_setprio(1);
#pragma unroll
    for (int mi = 0; mi < 4; ++mi)
#pragma unroll
      for (int ni = 0; ni < 4; ++ni)
        acc[mi][ni] = __builtin_amdgcn_mfma_f32_16x16x32_bf16(aF[mi], bF[ni], acc[mi][ni], 0, 0, 0);
    __builtin_amdgcn_s_setprio(0);
    __builtin_amdgcn_s_barrier();
    // ---- phase 2: A(4..7); stage half1 of kt+3; 16 MFMA
    bf16x8 aG[4];
#pragma unroll
    for (int mi = 0; mi < 4; ++mi)
      aG[mi] = *(const bf16x8*)&S[cur][rdA + (4 + mi) * 512];
    if (kt + 3 < NT) STAGE_H(kt + 3, 1);
    asm volatile("s_waitcnt lgkmcnt(0)" ::: "memory");
    __builtin_amdgcn_s_setprio(1);
#pragma unroll
    for (int mi = 0; mi < 4; ++mi)
#pragma unroll
      for (int ni = 0; ni < 4; ++ni)
        acc[4 + mi][ni] = __builtin_amdgcn_mfma_f32_16x16x32_bf16(aG[mi], bF[ni], acc[4 + mi][ni], 0, 0, 0);
    __builtin_amdgcn_s_setprio(0);
    __builtin_amdgcn_s_barrier();
  }

  const int mvalid = cnt - rb * 256;
#pragma unroll
  for (int mi = 0; mi < 8; ++mi)
#pragma unroll
    for (int r = 0; r < 4; ++r) {
      const int mrow = wr * 128 + mi * 16 + hi * 4 + r;
      if (mrow < mvalid) {
        const int tok = exit_idx[rb * 256 + mrow];
        float* orow = out + (size_t)tok * VOC + n0 + wc * 64 + lr16;
#pragma unroll
        for (int ni = 0; ni < 4; ++ni)
          __builtin_nontemporal_store(acc[mi][ni][r], &orow[ni * 16]);
      }
    }
}

// ---------------- host ----------------
extern "C" void kernel_launch(void* const* d_in, const int* in_sizes, int n_in,
                              void* d_out, int out_size, void* d_ws, size_t ws_size,
                              hipStream_t stream)
{
  const int*   x    = (const int*)d_in[0];
  const float* emb  = (const float*)d_in[1];
  const float* ln_g = (const float*)d_in[2];
  const float* ln_b = (const float*)d_in[3];
  const float* W1   = (const float*)d_in[4];
  const float* b1   = (const float*)d_in[5];
  const float* W2   = (const float*)d_in[6];
  const float* b2   = (const float*)d_in[7];
  const float* Wout = (const float*)d_in[8];
  float* out = (float*)d_out;

  char* p = (char*)d_ws;
  size_t off = 0;
  auto alloc = [&](size_t bytes) -> void* {
    void* r = p + off;
    off += (bytes + 255) & ~(size_t)255;
    return r;
  };
  u16* wsb = (u16*)d_ws;
  float* h    = (float*)alloc((size_t)TK * DIMC * 4);
  float* pbuf = (float*)alloc((size_t)2 * TK * DIMC * 4);   // gemm2 partials; hn planes alias
  u16* hn1 = (u16*)pbuf;
  u16* hn2 = hn1 + (size_t)TK * DIMC;
  u16* act1 = (u16*)alloc((size_t)2 * TK * DFFC * 2);       // act1 | act2 contiguous
  u16* act2 = act1 + (size_t)TK * DFFC;
  u16* Woutb = (u16*)alloc((size_t)VOC * DIMC * 2);
  u16* Wt = (u16*)alloc((size_t)2 * DFFC * DIMC * 2);       // shared by W1t / W2t (sequential)
  u16* hexit = (u16*)alloc((size_t)TK * DIMC * 2);
  int* exit_idx = (int*)alloc((size_t)TK * 4);
  int* surv_a   = (int*)alloc((size_t)TK * 4);
  int* surv_b   = (int*)alloc((size_t)TK * 4);
  int* cnts     = (int*)alloc(64 * 4);
  // cnts[0..2]=exit counts; cnts[4..6]=survivor counts; cnts[12]=TK

  const int offHn  = (int)(hn1  - wsb);
  const int offAct = (int)(act1 - wsb);
  const int offWob = (int)(Woutb- wsb);
  const int offWt  = (int)(Wt   - wsb);
  const int offHex = (int)(hexit- wsb);
  const int pstrHn  = TK * DIMC;
  const int pstrAct = TK * DFFC;
  const int pstrW   = DFFC * DIMC;

  k_init<<<TK, 256, 0, stream>>>(x, emb, h, surv_a, cnts);
  k_cvtb<<<2048, 256, 0, stream>>>(Wout, Woutb, VOC * DIMC / 4);
  int* surv_in  = surv_a;
  int* surv_out = surv_b;
  for (int i = 0; i < NL; ++i) {
    const int* pM = (i == 0) ? (cnts + 12) : (cnts + 4 + (i - 1));
    k_ln<<<TK, 256, 0, stream>>>(h, surv_in, pM, ln_g + i * DIMC, ln_b + i * DIMC, hn1, hn2);
    k_splitw<<<dim3(DIMC / 32, DFFC / 32), 256, 0, stream>>>(
        W1 + (size_t)i * DIMC * DFFC, DIMC, DFFC, Wt, Wt + (size_t)DFFC * DIMC);
    k_mlp1<<<256, 512, 0, stream>>>(
        wsb, offHn, pstrHn, offWt, pstrW, pM, b1 + (size_t)i * DFFC, act1, act2);
    k_splitw<<<dim3(DFFC / 32, DIMC / 32), 256, 0, stream>>>(
        W2 + (size_t)i * DFFC * DIMC, DFFC, DIMC, Wt, Wt + (size_t)DIMC * DFFC);
    k_mlp2<<<256, 512, 0, stream>>>(
        wsb, offAct, pstrAct, offWt, pstrW, pM, pbuf);
    k_decide<<<TK, 256, 0, stream>>>(h, pbuf, b2 + (size_t)i * DIMC,
        surv_in, surv_out, pM, cnts, exit_idx, hexit, i);
    k_logits<<<2000, 512, 0, stream>>>(wsb, offHex, offWob, cnts + i, exit_idx, out);
    int* tmp = surv_in; surv_in = surv_out; surv_out = tmp;
  }
}

// Round 10
// 1460.960 us; speedup vs baseline: 1.4717x; 1.2317x over previous
//
#include <hip/hip_runtime.h>
#include <hip/hip_bf16.h>
#include <stdint.h>

constexpr int TK   = 4096;   // B*S tokens
constexpr int DIMC = 1024;
constexpr int DFFC = 4096;
constexpr int VOC  = 32000;
constexpr int NL   = 3;

typedef __attribute__((ext_vector_type(8))) short bf16x8;
typedef __attribute__((ext_vector_type(8))) _Float16 half8;
typedef __attribute__((ext_vector_type(4))) float f32x4;
using u16 = unsigned short;

__device__ __forceinline__ u16 f2bf(float f) {
  unsigned int u = __float_as_uint(f);
  u += 0x7FFF + ((u >> 16) & 1);           // RNE; inputs finite
  return (u16)(u >> 16);
}

__device__ __forceinline__ void split16(float v, u16& hi, u16& lo) {
  _Float16 a = (_Float16)v;
  _Float16 b = (_Float16)(v - (float)a);
  hi = __builtin_bit_cast(u16, a);
  lo = __builtin_bit_cast(u16, b);
}

__device__ __forceinline__ float gelu_f(float x) {
  float x3 = x * x * x;
  return 0.5f * x * (1.0f + tanhf(0.7978845608028654f * (x + 0.044715f * x3)));
}

// async global->LDS, 16B/lane; LDS dest = wave-uniform base (+lane*16 in HW)
__device__ __forceinline__ void gll16(const void* g, void* l) {
  __builtin_amdgcn_global_load_lds(
      (const __attribute__((address_space(1))) unsigned int*)g,
      (__attribute__((address_space(3))) unsigned int*)l, 16, 0, 0);
}

// ---------------- init ----------------
__global__ __launch_bounds__(256) void k_init(const int* __restrict__ x,
    const float* __restrict__ emb, float* __restrict__ h,
    int* __restrict__ surv, int* __restrict__ cnts) {
  const int t = blockIdx.x, tid = threadIdx.x;
  if (t == 0 && tid < 16) cnts[tid] = (tid == 12) ? TK : 0;
  if (tid == 0) surv[t] = t;
  const int tok = x[t];
  ((float4*)(h + (size_t)t * DIMC))[tid] =
      ((const float4*)(emb + (size_t)tok * DIMC))[tid];
}

// ---------------- layernorm -> 2 fp16 planes (x16 scale) ----------------
__global__ __launch_bounds__(256) void k_ln(const float* __restrict__ h,
    const int* __restrict__ surv, const int* __restrict__ pM,
    const float* __restrict__ g, const float* __restrict__ b,
    u16* __restrict__ hn1, u16* __restrict__ hn2) {
  const int bidx = blockIdx.x;
  if (bidx >= *pM) return;
  const int t = surv[bidx];
  const int tid = threadIdx.x;
  const int lane = tid & 63, wid = tid >> 6;
  __shared__ float sm[4];
  float4 v = ((const float4*)(h + (size_t)t * DIMC))[tid];
  float s = v.x + v.y + v.z + v.w;
#pragma unroll
  for (int o = 32; o; o >>= 1) s += __shfl_down(s, o);
  if (lane == 0) sm[wid] = s;
  __syncthreads();
  const float mean = (sm[0] + sm[1] + sm[2] + sm[3]) * (1.0f / DIMC);
  __syncthreads();
  float4 d;
  d.x = v.x - mean; d.y = v.y - mean; d.z = v.z - mean; d.w = v.w - mean;
  float q = d.x * d.x + d.y * d.y + d.z * d.z + d.w * d.w;
#pragma unroll
  for (int o = 32; o; o >>= 1) q += __shfl_down(q, o);
  if (lane == 0) sm[wid] = q;
  __syncthreads();
  const float var = (sm[0] + sm[1] + sm[2] + sm[3]) * (1.0f / DIMC);
  const float rstd = 1.0f / sqrtf(var + 1e-5f);
  float4 gg = ((const float4*)g)[tid];
  float4 bb = ((const float4*)b)[tid];
  float o4[4];
  o4[0] = (d.x * rstd * gg.x + bb.x) * 16.f;
  o4[1] = (d.y * rstd * gg.y + bb.y) * 16.f;
  o4[2] = (d.z * rstd * gg.z + bb.z) * 16.f;
  o4[3] = (d.w * rstd * gg.w + bb.w) * 16.f;
  ushort4 u1, u2;
  split16(o4[0], u1.x, u2.x); split16(o4[1], u1.y, u2.y);
  split16(o4[2], u1.z, u2.z); split16(o4[3], u1.w, u2.w);
  ((ushort4*)(hn1 + (size_t)bidx * DIMC))[tid] = u1;
  ((ushort4*)(hn2 + (size_t)bidx * DIMC))[tid] = u2;
}

// ---------------- weight transpose + fp16 2-split (x256 scale) ----------------
__global__ __launch_bounds__(256) void k_splitw(const float* __restrict__ W,
    int K, int N, u16* __restrict__ O1, u16* __restrict__ O2) {
  __shared__ float t[32][33];
  const int bk = blockIdx.x * 32, bn = blockIdx.y * 32;
  const int lx = threadIdx.x & 31, ly = threadIdx.x >> 5;
#pragma unroll
  for (int i = 0; i < 32; i += 8)
    t[ly + i][lx] = W[(size_t)(bk + ly + i) * N + bn + lx];
  __syncthreads();
#pragma unroll
  for (int i = 0; i < 32; i += 8) {
    float v = t[lx][ly + i] * 256.f;
    u16 h1, h2; split16(v, h1, h2);
    const size_t o = (size_t)(bn + ly + i) * K + bk + lx;
    O1[o] = h1; O2[o] = h2;
  }
}

// ---------------- f32 -> bf16 bulk convert (Wout, once per call) ----------------
__global__ __launch_bounds__(256) void k_cvtb(const float* __restrict__ in,
    u16* __restrict__ o, int n4) {
  int i = blockIdx.x * blockDim.x + threadIdx.x;
  const int stride = gridDim.x * blockDim.x;
  for (; i < n4; i += stride) {
    float4 v = ((const float4*)in)[i];
    ushort4 u;
    u.x = f2bf(v.x); u.y = f2bf(v.y); u.z = f2bf(v.z); u.w = f2bf(v.w);
    ((ushort4*)o)[i] = u;
  }
}

// ============ MLP GEMM: 128x128 tile, 4 waves (64x64), BK=64, single-buf 64KB ============
// R4-proven structure (2 blocks/CU, syncthreads-drained), fragment-linear LDS
// (conflict-free), rb-fastest XCD swizzle.  C ~= (A1+A2)(B1+B2)^T 3-term.
// EPI==0: O1,O2 = split64(gelu(C*osc + bias))    EPI==1: PO[z-slab] = C*osc
template<int EPI, int LDK>
__global__ __launch_bounds__(256, 2) void k_mlp(
    const u16* __restrict__ wsb,
    int offA, int pstrA,
    int offB, int pstrB,
    const int* __restrict__ pM, int Kpart,
    const float* __restrict__ bias,
    u16* __restrict__ O1, u16* __restrict__ O2,
    float* __restrict__ PO, float osc)
{
  // rb-fastest XCD-partitioned swizzle: concurrent blocks on an XCD share B-slabs
  const int x = blockIdx.x & 7, g = blockIdx.x >> 3;
  const int rb = g & 31;
  int cb, z;
  if constexpr (EPI == 0) {            // grid 1024 = 8 x (32 rb x 4 cbl)
    cb = x * 4 + (g >> 5); z = 0;
  } else {                             // grid 512 = 8 x (32 rb x 2); cz = cb(8) x z(2)
    const int cz = x * 2 + (g >> 5);
    cb = cz & 7; z = cz >> 3;
  }
  const int M = *pM;
  if (rb * 128 >= M) return;
  const int n0 = cb * 128;
  const int kz = z * Kpart;

  __shared__ u16 S[4 * 8192];          // A1|A2|B1|B2, each 128x64 (16 subtiles of 512)
  const int tid = threadIdx.x, w = tid >> 6, l = tid & 63;
  const int lr16 = l & 15, hi = l >> 4;

  // staging: wave w stages tensor w (16 gll16 of 1KB)
  int offT;
  if (w == 0) offT = offA;
  else if (w == 1) offT = offA + pstrA;
  else if (w == 2) offT = offB;
  else offT = offB + pstrB;
  const int row0 = (w < 2) ? (rb * 128) : n0;
  const int gbase = offT + (row0 + lr16) * LDK + kz + hi * 8;

  const int wr = w >> 1, wc = w & 1;   // 2x2 wave grid, wave tile 64x64
  f32x4 acc[4][4];
#pragma unroll
  for (int mi = 0; mi < 4; ++mi)
#pragma unroll
    for (int ni = 0; ni < 4; ++ni) acc[mi][ni] = (f32x4){0.f, 0.f, 0.f, 0.f};

  const int NT = Kpart / 64;
  for (int kt = 0; kt < NT; ++kt) {
    __syncthreads();                   // prior reads of S complete
#pragma unroll
    for (int s = 0; s < 16; ++s) {     // j = s>>1 (row-block), ks = s&1 (k-half)
      const int j = s >> 1, ks = s & 1;
      gll16(wsb + (size_t)(gbase + j * 16 * LDK + ks * 32 + kt * 64),
            (void*)&S[w * 8192 + (j * 2 + ks) * 512]);
    }
    __syncthreads();                   // compiler drains vmcnt(0) before barrier
#pragma unroll
    for (int ks = 0; ks < 2; ++ks) {
      half8 a1v[4], a2v[4], b1v[4], b2v[4];
#pragma unroll
      for (int mi = 0; mi < 4; ++mi) {
        const int sub = ((wr * 4 + mi) * 2 + ks) * 512 + l * 8;
        a1v[mi] = *(const half8*)&S[sub];
        a2v[mi] = *(const half8*)&S[8192 + sub];
      }
#pragma unroll
      for (int ni = 0; ni < 4; ++ni) {
        const int sub = ((wc * 4 + ni) * 2 + ks) * 512 + l * 8;
        b1v[ni] = *(const half8*)&S[16384 + sub];
        b2v[ni] = *(const half8*)&S[24576 + sub];
      }
      __builtin_amdgcn_s_setprio(1);
#pragma unroll
      for (int mi = 0; mi < 4; ++mi)
#pragma unroll
        for (int ni = 0; ni < 4; ++ni) {
          f32x4 c = acc[mi][ni];
          c = __builtin_amdgcn_mfma_f32_16x16x32_f16(a2v[mi], b1v[ni], c, 0, 0, 0);
          c = __builtin_amdgcn_mfma_f32_16x16x32_f16(a1v[mi], b2v[ni], c, 0, 0, 0);
          c = __builtin_amdgcn_mfma_f32_16x16x32_f16(a1v[mi], b1v[ni], c, 0, 0, 0);
          acc[mi][ni] = c;
        }
      __builtin_amdgcn_s_setprio(0);
    }
  }

#pragma unroll
  for (int mi = 0; mi < 4; ++mi)
#pragma unroll
    for (int ni = 0; ni < 4; ++ni) {
      const int n = n0 + wc * 64 + ni * 16 + lr16;
#pragma unroll
      for (int r = 0; r < 4; ++r) {
        const int m = rb * 128 + wr * 64 + mi * 16 + hi * 4 + r;
        float v = acc[mi][ni][r] * osc;
        if constexpr (EPI == 0) {
          v = gelu_f(v + bias[n]) * 64.f;
          u16 h1, h2; split16(v, h1, h2);
          O1[(size_t)m * DFFC + n] = h1;
          O2[(size_t)m * DFFC + n] = h2;
        } else {
          PO[(size_t)(z * TK + m) * DIMC + n] = v;
        }
      }
    }
}

// ---------------- decide: o = h + p0 + p1 + b2; cos; route token ----------------
__global__ __launch_bounds__(256) void k_decide(
    float* __restrict__ h, const float* __restrict__ p,
    const float* __restrict__ bias,
    const int* __restrict__ surv_in, int* __restrict__ surv_out,
    const int* __restrict__ pM, int* __restrict__ cnts,
    int* __restrict__ exit_idx, u16* __restrict__ hexit,
    int stage)
{
  const int bidx = blockIdx.x;
  if (bidx >= *pM) return;
  const int t = surv_in[bidx];
  const int tid = threadIdx.x;
  const int lane = tid & 63, wid = tid >> 6;
  __shared__ float sm[12];
  __shared__ int sif[2];
  float4 a  = ((const float4*)(h + (size_t)t * DIMC))[tid];
  float4 p0 = ((const float4*)(p + (size_t)bidx * DIMC))[tid];
  float4 p1 = ((const float4*)(p + (size_t)(TK + bidx) * DIMC))[tid];
  float4 bb = ((const float4*)bias)[tid];
  float4 o;
  o.x = a.x + p0.x + p1.x + bb.x;
  o.y = a.y + p0.y + p1.y + bb.y;
  o.z = a.z + p0.z + p1.z + bb.z;
  o.w = a.w + p0.w + p1.w + bb.w;
  float hh = a.x * a.x + a.y * a.y + a.z * a.z + a.w * a.w;
  float ho = a.x * o.x + a.y * o.y + a.z * o.z + a.w * o.w;
  float oo = o.x * o.x + o.y * o.y + o.z * o.z + o.w * o.w;
#pragma unroll
  for (int off = 32; off; off >>= 1) {
    hh += __shfl_down(hh, off);
    ho += __shfl_down(ho, off);
    oo += __shfl_down(oo, off);
  }
  if (lane == 0) { sm[wid] = hh; sm[4 + wid] = ho; sm[8 + wid] = oo; }
  __syncthreads();
  if (tid == 0) {
    int take;
    if (stage == NL - 1) take = 1;
    else {
      const float HH = sm[0] + sm[1] + sm[2] + sm[3];
      const float HO = sm[4] + sm[5] + sm[6] + sm[7];
      const float OO = sm[8] + sm[9] + sm[10] + sm[11];
      const float cosv = HO / (sqrtf(HH) * sqrtf(OO) + 1e-8f);
      take = (cosv >= 0.98f) ? 1 : 0;
    }
    int pos;
    if (take) {
      pos = atomicAdd(&cnts[stage], 1);
      exit_idx[pos] = t;
    } else {
      pos = atomicAdd(&cnts[4 + stage], 1);
      surv_out[pos] = t;
    }
    sif[0] = take; sif[1] = pos;
  }
  __syncthreads();
  if (sif[0]) {
    u16* dst = hexit + (size_t)sif[1] * DIMC;
    ushort4 u;
    u.x = f2bf(o.x); u.y = f2bf(o.y); u.z = f2bf(o.z); u.w = f2bf(o.w);
    ((ushort4*)dst)[tid] = u;
  } else {
    ((float4*)(h + (size_t)t * DIMC))[tid] = o;
  }
}

// ============ logits: bf16, 256x128 tile, BK=32, dbuf 48KB, 8 waves, 2 blk/CU ============
// counted-vmcnt (R8-proven loop), rb-fastest XCD-partitioned swizzle so the 64
// concurrent blocks of an XCD share 4 Wout slabs (1 MB, L2-resident, 16x reuse).
__global__ __launch_bounds__(512, 4) void k_logits(
    const u16* __restrict__ wsb, int offA, int offB,
    const int* __restrict__ pcnt,
    const int* __restrict__ exit_idx,
    float* __restrict__ out)
{
  const int x = blockIdx.x & 7, g = blockIdx.x >> 3;   // grid 4096 = 8 x 512
  const int rb = g & 15;
  const int cb = x * 32 + (g >> 4);                    // 0..255
  if (cb >= VOC / 128) return;                         // 250 real cb
  const int cnt = *pcnt;
  if (rb * 256 >= cnt) return;
  const int n0 = cb * 128;

  __shared__ u16 S[2][12288];          // [A(16 subtiles) | B(8 subtiles)] x 512u16; 48KB
  const int tid = threadIdx.x, w = tid >> 6, l = tid & 63;
  const int lr16 = l & 15, hi = l >> 4;

  int goff[3], loff[3];
#pragma unroll
  for (int q = 0; q < 3; ++q) {
    const int bi = w * 3 + q;          // 24 subtiles: A 0..15, B 16..23
    if (bi < 16) {
      goff[q] = offA + (rb * 256 + bi * 16 + lr16) * DIMC + hi * 8;
      loff[q] = bi * 512;
    } else {
      const int j = bi - 16;
      goff[q] = offB + (n0 + j * 16 + lr16) * DIMC + hi * 8;
      loff[q] = 8192 + j * 512;
    }
  }

  const int wr = w >> 1, wc = w & 1;   // 4M x 2N wave grid, wave tile 64x64
  f32x4 acc[4][4];
#pragma unroll
  for (int mi = 0; mi < 4; ++mi)
#pragma unroll
    for (int ni = 0; ni < 4; ++ni) acc[mi][ni] = (f32x4){0.f, 0.f, 0.f, 0.f};

  auto STAGE = [&](int buf, int kt) {
#pragma unroll
    for (int q = 0; q < 3; ++q)
      gll16(wsb + (size_t)(goff[q] + kt * 32), (void*)&S[buf][loff[q]]);
  };

  STAGE(0, 0);
  STAGE(1, 1);
  const int NT = DIMC / 32;            // 32
  for (int kt = 0; kt < NT; ++kt) {
    const int cur = kt & 1;
    if (kt + 1 < NT) asm volatile("s_waitcnt vmcnt(3)" ::: "memory");
    else             asm volatile("s_waitcnt vmcnt(0)" ::: "memory");
    __builtin_amdgcn_s_barrier();
    bf16x8 aF[4], bF[4];
#pragma unroll
    for (int mi = 0; mi < 4; ++mi)
      aF[mi] = *(const bf16x8*)&S[cur][(wr * 4 + mi) * 512 + l * 8];
#pragma unroll
    for (int ni = 0; ni < 4; ++ni)
      bF[ni] = *(const bf16x8*)&S[cur][8192 + (wc * 4 + ni) * 512 + l * 8];
    __builtin_amdgcn_s_setprio(1);
#pragma unroll
    for (int mi = 0; mi < 4; ++mi)
#pragma unroll
      for (int ni = 0; ni < 4; ++ni)
        acc[mi][ni] = __builtin_amdgcn_mfma_f32_16x16x32_bf16(aF[mi], bF[ni], acc[mi][ni], 0, 0, 0);
    __builtin_amdgcn_s_setprio(0);
    asm volatile("s_waitcnt lgkmcnt(0)" ::: "memory");
    __builtin_amdgcn_s_barrier();
    if (kt + 2 < NT) STAGE(cur, kt + 2);
  }

  const int mvalid = cnt - rb * 256;
#pragma unroll
  for (int mi = 0; mi < 4; ++mi)
#pragma unroll
    for (int r = 0; r < 4; ++r) {
      const int mrow = wr * 64 + mi * 16 + hi * 4 + r;
      if (mrow < mvalid) {
        const int tok = exit_idx[rb * 256 + mrow];
        float* orow = out + (size_t)tok * VOC + n0 + wc * 64 + lr16;
#pragma unroll
        for (int ni = 0; ni < 4; ++ni)
          __builtin_nontemporal_store(acc[mi][ni][r], &orow[ni * 16]);
      }
    }
}

// ---------------- host ----------------
extern "C" void kernel_launch(void* const* d_in, const int* in_sizes, int n_in,
                              void* d_out, int out_size, void* d_ws, size_t ws_size,
                              hipStream_t stream)
{
  const int*   x    = (const int*)d_in[0];
  const float* emb  = (const float*)d_in[1];
  const float* ln_g = (const float*)d_in[2];
  const float* ln_b = (const float*)d_in[3];
  const float* W1   = (const float*)d_in[4];
  const float* b1   = (const float*)d_in[5];
  const float* W2   = (const float*)d_in[6];
  const float* b2   = (const float*)d_in[7];
  const float* Wout = (const float*)d_in[8];
  float* out = (float*)d_out;

  char* p = (char*)d_ws;
  size_t off = 0;
  auto alloc = [&](size_t bytes) -> void* {
    void* r = p + off;
    off += (bytes + 255) & ~(size_t)255;
    return r;
  };
  u16* wsb = (u16*)d_ws;
  float* h    = (float*)alloc((size_t)TK * DIMC * 4);
  float* pbuf = (float*)alloc((size_t)2 * TK * DIMC * 4);   // gemm2 partials; hn planes alias
  u16* hn1 = (u16*)pbuf;
  u16* hn2 = hn1 + (size_t)TK * DIMC;
  u16* act1 = (u16*)alloc((size_t)2 * TK * DFFC * 2);       // act1 | act2 contiguous
  u16* act2 = act1 + (size_t)TK * DFFC;
  u16* Woutb = (u16*)alloc((size_t)VOC * DIMC * 2);
  u16* Wt = (u16*)alloc((size_t)2 * DFFC * DIMC * 2);       // shared by W1t / W2t (sequential)
  u16* hexit = (u16*)alloc((size_t)TK * DIMC * 2);
  int* exit_idx = (int*)alloc((size_t)TK * 4);
  int* surv_a   = (int*)alloc((size_t)TK * 4);
  int* surv_b   = (int*)alloc((size_t)TK * 4);
  int* cnts     = (int*)alloc(64 * 4);
  // cnts[0..2]=exit counts; cnts[4..6]=survivor counts; cnts[12]=TK

  const int offHn  = (int)(hn1  - wsb);
  const int offAct = (int)(act1 - wsb);
  const int offWob = (int)(Woutb- wsb);
  const int offWt  = (int)(Wt   - wsb);
  const int offHex = (int)(hexit- wsb);
  const int pstrHn  = TK * DIMC;
  const int pstrAct = TK * DFFC;
  const int pstrW   = DFFC * DIMC;

  k_init<<<TK, 256, 0, stream>>>(x, emb, h, surv_a, cnts);
  k_cvtb<<<2048, 256, 0, stream>>>(Wout, Woutb, VOC * DIMC / 4);
  int* surv_in  = surv_a;
  int* surv_out = surv_b;
  for (int i = 0; i < NL; ++i) {
    const int* pM = (i == 0) ? (cnts + 12) : (cnts + 4 + (i - 1));
    k_ln<<<TK, 256, 0, stream>>>(h, surv_in, pM, ln_g + i * DIMC, ln_b + i * DIMC, hn1, hn2);
    k_splitw<<<dim3(DIMC / 32, DFFC / 32), 256, 0, stream>>>(
        W1 + (size_t)i * DIMC * DFFC, DIMC, DFFC, Wt, Wt + (size_t)DFFC * DIMC);
    // gemm1: grid 1024 = 8 XCD x (32 rb x 4 cbl)
    k_mlp<0, DIMC><<<1024, 256, 0, stream>>>(
        wsb, offHn, pstrHn, offWt, pstrW, pM, DIMC,
        b1 + (size_t)i * DFFC, act1, act2, nullptr, 1.f / 4096.f);
    k_splitw<<<dim3(DFFC / 32, DIMC / 32), 256, 0, stream>>>(
        W2 + (size_t)i * DFFC * DIMC, DFFC, DIMC, Wt, Wt + (size_t)DIMC * DFFC);
    // gemm2: grid 512 = 8 XCD x (32 rb x 2 cz), split-K2
    k_mlp<1, DFFC><<<512, 256, 0, stream>>>(
        wsb, offAct, pstrAct, offWt, pstrW, pM, DFFC / 2,
        nullptr, nullptr, nullptr, pbuf, 1.f / 16384.f);
    k_decide<<<TK, 256, 0, stream>>>(h, pbuf, b2 + (size_t)i * DIMC,
        surv_in, surv_out, pM, cnts, exit_idx, hexit, i);
    // logits: grid 4096 = 8 XCD x (16 rb x 32 cbl), cb>=250 idle
    k_logits<<<4096, 512, 0, stream>>>(wsb, offHex, offWob, cnts + i, exit_idx, out);
    int* tmp = surv_in; surv_in = surv_out; surv_out = tmp;
  }
}

// Round 11
// 1414.560 us; speedup vs baseline: 1.5200x; 1.0328x over previous
//
#include <hip/hip_runtime.h>
#include <hip/hip_bf16.h>
#include <stdint.h>

constexpr int TK   = 4096;   // B*S tokens
constexpr int DIMC = 1024;
constexpr int DFFC = 4096;
constexpr int VOC  = 32000;
constexpr int NL   = 3;

typedef __attribute__((ext_vector_type(8))) short bf16x8;
typedef __attribute__((ext_vector_type(8))) _Float16 half8;
typedef __attribute__((ext_vector_type(4))) float f32x4;
using u16 = unsigned short;

__device__ __forceinline__ u16 f2bf(float f) {
  unsigned int u = __float_as_uint(f);
  u += 0x7FFF + ((u >> 16) & 1);           // RNE; inputs finite
  return (u16)(u >> 16);
}

__device__ __forceinline__ void split16(float v, u16& hi, u16& lo) {
  _Float16 a = (_Float16)v;
  _Float16 b = (_Float16)(v - (float)a);
  hi = __builtin_bit_cast(u16, a);
  lo = __builtin_bit_cast(u16, b);
}

__device__ __forceinline__ float gelu_f(float x) {
  float x3 = x * x * x;
  return 0.5f * x * (1.0f + tanhf(0.7978845608028654f * (x + 0.044715f * x3)));
}

// async global->LDS, 16B/lane; LDS dest = wave-uniform base (+lane*16 in HW)
__device__ __forceinline__ void gll16(const void* g, void* l) {
  __builtin_amdgcn_global_load_lds(
      (const __attribute__((address_space(1))) unsigned int*)g,
      (__attribute__((address_space(3))) unsigned int*)l, 16, 0, 0);
}

// ---------------- init ----------------
__global__ __launch_bounds__(256) void k_init(const int* __restrict__ x,
    const float* __restrict__ emb, float* __restrict__ h,
    int* __restrict__ surv, int* __restrict__ cnts) {
  const int t = blockIdx.x, tid = threadIdx.x;
  if (t == 0 && tid < 16) cnts[tid] = (tid == 12) ? TK : 0;
  if (tid == 0) surv[t] = t;
  const int tok = x[t];
  ((float4*)(h + (size_t)t * DIMC))[tid] =
      ((const float4*)(emb + (size_t)tok * DIMC))[tid];
}

// ---------------- layernorm -> 2 fp16 planes (x16 scale) ----------------
__global__ __launch_bounds__(256) void k_ln(const float* __restrict__ h,
    const int* __restrict__ surv, const int* __restrict__ pM,
    const float* __restrict__ g, const float* __restrict__ b,
    u16* __restrict__ hn1, u16* __restrict__ hn2) {
  const int bidx = blockIdx.x;
  if (bidx >= *pM) return;
  const int t = surv[bidx];
  const int tid = threadIdx.x;
  const int lane = tid & 63, wid = tid >> 6;
  __shared__ float sm[4];
  float4 v = ((const float4*)(h + (size_t)t * DIMC))[tid];
  float s = v.x + v.y + v.z + v.w;
#pragma unroll
  for (int o = 32; o; o >>= 1) s += __shfl_down(s, o);
  if (lane == 0) sm[wid] = s;
  __syncthreads();
  const float mean = (sm[0] + sm[1] + sm[2] + sm[3]) * (1.0f / DIMC);
  __syncthreads();
  float4 d;
  d.x = v.x - mean; d.y = v.y - mean; d.z = v.z - mean; d.w = v.w - mean;
  float q = d.x * d.x + d.y * d.y + d.z * d.z + d.w * d.w;
#pragma unroll
  for (int o = 32; o; o >>= 1) q += __shfl_down(q, o);
  if (lane == 0) sm[wid] = q;
  __syncthreads();
  const float var = (sm[0] + sm[1] + sm[2] + sm[3]) * (1.0f / DIMC);
  const float rstd = 1.0f / sqrtf(var + 1e-5f);
  float4 gg = ((const float4*)g)[tid];
  float4 bb = ((const float4*)b)[tid];
  float o4[4];
  o4[0] = (d.x * rstd * gg.x + bb.x) * 16.f;
  o4[1] = (d.y * rstd * gg.y + bb.y) * 16.f;
  o4[2] = (d.z * rstd * gg.z + bb.z) * 16.f;
  o4[3] = (d.w * rstd * gg.w + bb.w) * 16.f;
  ushort4 u1, u2;
  split16(o4[0], u1.x, u2.x); split16(o4[1], u1.y, u2.y);
  split16(o4[2], u1.z, u2.z); split16(o4[3], u1.w, u2.w);
  ((ushort4*)(hn1 + (size_t)bidx * DIMC))[tid] = u1;
  ((ushort4*)(hn2 + (size_t)bidx * DIMC))[tid] = u2;
}

// ---------------- weight transpose + fp16 2-split (x256 scale), 64x64, ushort4 writes ----
// in W[K][N] f32  ->  O1,O2 [N][K] fp16
__global__ __launch_bounds__(256) void k_splitw(const float* __restrict__ W,
    int K, int N, u16* __restrict__ O1, u16* __restrict__ O2) {
  __shared__ float t[64][65];
  const int bk = blockIdx.x * 64, bn = blockIdx.y * 64;
  const int lx = threadIdx.x & 63, ly = threadIdx.x >> 6;   // 4 rows per pass
#pragma unroll
  for (int i = 0; i < 64; i += 4)
    t[ly + i][lx] = W[(size_t)(bk + ly + i) * N + bn + lx];
  __syncthreads();
  const int n4 = threadIdx.x >> 4;         // 0..15
  const int kq = (threadIdx.x & 15) * 4;   // 0..60
#pragma unroll
  for (int j = 0; j < 4; ++j) {
    const int n = j * 16 + n4;
    ushort4 h1, h2;
    {
      float v0 = t[kq + 0][n] * 256.f, v1 = t[kq + 1][n] * 256.f;
      float v2 = t[kq + 2][n] * 256.f, v3 = t[kq + 3][n] * 256.f;
      split16(v0, h1.x, h2.x); split16(v1, h1.y, h2.y);
      split16(v2, h1.z, h2.z); split16(v3, h1.w, h2.w);
    }
    const size_t o = (size_t)(bn + n) * K + bk + kq;
    *(ushort4*)&O1[o] = h1;
    *(ushort4*)&O2[o] = h2;
  }
}

// ---------------- f32 -> bf16 bulk convert (Wout, once per call) ----------------
__global__ __launch_bounds__(256) void k_cvtb(const float* __restrict__ in,
    u16* __restrict__ o, int n4) {
  int i = blockIdx.x * blockDim.x + threadIdx.x;
  const int stride = gridDim.x * blockDim.x;
  for (; i < n4; i += stride) {
    float4 v = ((const float4*)in)[i];
    ushort4 u;
    u.x = f2bf(v.x); u.y = f2bf(v.y); u.z = f2bf(v.z); u.w = f2bf(v.w);
    ((ushort4*)o)[i] = u;
  }
}

// ============ MLP GEMM: 128x128 tile, 4 waves (64x64), BK=32, counted-vmcnt dbuf ============
// 2x32KB LDS double buffer, 2 blocks/CU, vmcnt(8) steady / vmcnt(0) epilogue
// (R8/R10-logits-proven loop), fragment-linear LDS, rb-fastest XCD swizzle.
// C ~= (A1+A2)(B1+B2)^T 3-term.
// EPI==0: O1,O2 = split64(gelu(C*osc + bias))    EPI==1: PO[z-slab] = C*osc
template<int EPI, int LDK>
__global__ __launch_bounds__(256, 2) void k_mlp(
    const u16* __restrict__ wsb,
    int offA, int pstrA,
    int offB, int pstrB,
    const int* __restrict__ pM, int Kpart,
    const float* __restrict__ bias,
    u16* __restrict__ O1, u16* __restrict__ O2,
    float* __restrict__ PO, float osc)
{
  // rb-fastest XCD-partitioned swizzle: concurrent blocks on an XCD share B-slabs
  const int x = blockIdx.x & 7, g = blockIdx.x >> 3;
  const int rb = g & 31;
  int cb, z;
  if constexpr (EPI == 0) {            // grid 1024 = 8 x (32 rb x 4 cbl)
    cb = x * 4 + (g >> 5); z = 0;
  } else {                             // grid 512 = 8 x (32 rb x 2); cz = cb(8) x z(2)
    const int cz = x * 2 + (g >> 5);
    cb = cz & 7; z = cz >> 3;
  }
  const int M = *pM;
  if (rb * 128 >= M) return;
  const int n0 = cb * 128;
  const int kz = z * Kpart;

  __shared__ u16 S[2][16384];          // dbuf x [A1|A2|B1|B2] x 8 subtiles(16x32) of 512u16
  const int tid = threadIdx.x, w = tid >> 6, l = tid & 63;
  const int lr16 = l & 15, hi = l >> 4;

  // staging: wave w stages tensor w (8 gll16 of 1KB per tile)
  int offT;
  if (w == 0) offT = offA;
  else if (w == 1) offT = offA + pstrA;
  else if (w == 2) offT = offB;
  else offT = offB + pstrB;
  const int row0 = (w < 2) ? (rb * 128) : n0;
  int goff[8];
#pragma unroll
  for (int j = 0; j < 8; ++j)
    goff[j] = offT + (row0 + j * 16 + lr16) * LDK + kz + hi * 8;

  const int wr = w >> 1, wc = w & 1;   // 2x2 wave grid, wave tile 64x64
  f32x4 acc[4][4];
#pragma unroll
  for (int mi = 0; mi < 4; ++mi)
#pragma unroll
    for (int ni = 0; ni < 4; ++ni) acc[mi][ni] = (f32x4){0.f, 0.f, 0.f, 0.f};

  auto STAGE = [&](int buf, int kt) {
#pragma unroll
    for (int j = 0; j < 8; ++j)
      gll16(wsb + (size_t)(goff[j] + kt * 32), (void*)&S[buf][w * 4096 + j * 512]);
  };

  STAGE(0, 0);
  STAGE(1, 1);
  const int NT = Kpart / 32;
  for (int kt = 0; kt < NT; ++kt) {
    const int cur = kt & 1;
    if (kt + 1 < NT) asm volatile("s_waitcnt vmcnt(8)" ::: "memory");
    else             asm volatile("s_waitcnt vmcnt(0)" ::: "memory");
    __builtin_amdgcn_s_barrier();
    half8 a1v[4], a2v[4], b1v[4], b2v[4];
#pragma unroll
    for (int mi = 0; mi < 4; ++mi) {
      const int sub = (wr * 4 + mi) * 512 + l * 8;
      a1v[mi] = *(const half8*)&S[cur][sub];
      a2v[mi] = *(const half8*)&S[cur][4096 + sub];
    }
#pragma unroll
    for (int ni = 0; ni < 4; ++ni) {
      const int sub = (wc * 4 + ni) * 512 + l * 8;
      b1v[ni] = *(const half8*)&S[cur][8192 + sub];
      b2v[ni] = *(const half8*)&S[cur][12288 + sub];
    }
    __builtin_amdgcn_s_setprio(1);
#pragma unroll
    for (int mi = 0; mi < 4; ++mi)
#pragma unroll
      for (int ni = 0; ni < 4; ++ni) {
        f32x4 c = acc[mi][ni];
        c = __builtin_amdgcn_mfma_f32_16x16x32_f16(a2v[mi], b1v[ni], c, 0, 0, 0);
        c = __builtin_amdgcn_mfma_f32_16x16x32_f16(a1v[mi], b2v[ni], c, 0, 0, 0);
        c = __builtin_amdgcn_mfma_f32_16x16x32_f16(a1v[mi], b1v[ni], c, 0, 0, 0);
        acc[mi][ni] = c;
      }
    __builtin_amdgcn_s_setprio(0);
    asm volatile("s_waitcnt lgkmcnt(0)" ::: "memory");
    __builtin_amdgcn_s_barrier();
    if (kt + 2 < NT) STAGE(cur, kt + 2);
  }

#pragma unroll
  for (int mi = 0; mi < 4; ++mi)
#pragma unroll
    for (int ni = 0; ni < 4; ++ni) {
      const int n = n0 + wc * 64 + ni * 16 + lr16;
#pragma unroll
      for (int r = 0; r < 4; ++r) {
        const int m = rb * 128 + wr * 64 + mi * 16 + hi * 4 + r;
        float v = acc[mi][ni][r] * osc;
        if constexpr (EPI == 0) {
          v = gelu_f(v + bias[n]) * 64.f;
          u16 h1, h2; split16(v, h1, h2);
          O1[(size_t)m * DFFC + n] = h1;
          O2[(size_t)m * DFFC + n] = h2;
        } else {
          PO[(size_t)(z * TK + m) * DIMC + n] = v;
        }
      }
    }
}

// ---------------- decide: o = h + p0 + p1 + b2; cos; route token ----------------
__global__ __launch_bounds__(256) void k_decide(
    float* __restrict__ h, const float* __restrict__ p,
    const float* __restrict__ bias,
    const int* __restrict__ surv_in, int* __restrict__ surv_out,
    const int* __restrict__ pM, int* __restrict__ cnts,
    int* __restrict__ exit_idx, u16* __restrict__ hexit,
    int stage)
{
  const int bidx = blockIdx.x;
  if (bidx >= *pM) return;
  const int t = surv_in[bidx];
  const int tid = threadIdx.x;
  const int lane = tid & 63, wid = tid >> 6;
  __shared__ float sm[12];
  __shared__ int sif[2];
  float4 a  = ((const float4*)(h + (size_t)t * DIMC))[tid];
  float4 p0 = ((const float4*)(p + (size_t)bidx * DIMC))[tid];
  float4 p1 = ((const float4*)(p + (size_t)(TK + bidx) * DIMC))[tid];
  float4 bb = ((const float4*)bias)[tid];
  float4 o;
  o.x = a.x + p0.x + p1.x + bb.x;
  o.y = a.y + p0.y + p1.y + bb.y;
  o.z = a.z + p0.z + p1.z + bb.z;
  o.w = a.w + p0.w + p1.w + bb.w;
  float hh = a.x * a.x + a.y * a.y + a.z * a.z + a.w * a.w;
  float ho = a.x * o.x + a.y * o.y + a.z * o.z + a.w * o.w;
  float oo = o.x * o.x + o.y * o.y + o.z * o.z + o.w * o.w;
#pragma unroll
  for (int off = 32; off; off >>= 1) {
    hh += __shfl_down(hh, off);
    ho += __shfl_down(ho, off);
    oo += __shfl_down(oo, off);
  }
  if (lane == 0) { sm[wid] = hh; sm[4 + wid] = ho; sm[8 + wid] = oo; }
  __syncthreads();
  if (tid == 0) {
    int take;
    if (stage == NL - 1) take = 1;
    else {
      const float HH = sm[0] + sm[1] + sm[2] + sm[3];
      const float HO = sm[4] + sm[5] + sm[6] + sm[7];
      const float OO = sm[8] + sm[9] + sm[10] + sm[11];
      const float cosv = HO / (sqrtf(HH) * sqrtf(OO) + 1e-8f);
      take = (cosv >= 0.98f) ? 1 : 0;
    }
    int pos;
    if (take) {
      pos = atomicAdd(&cnts[stage], 1);
      exit_idx[pos] = t;
    } else {
      pos = atomicAdd(&cnts[4 + stage], 1);
      surv_out[pos] = t;
    }
    sif[0] = take; sif[1] = pos;
  }
  __syncthreads();
  if (sif[0]) {
    u16* dst = hexit + (size_t)sif[1] * DIMC;
    ushort4 u;
    u.x = f2bf(o.x); u.y = f2bf(o.y); u.z = f2bf(o.z); u.w = f2bf(o.w);
    ((ushort4*)dst)[tid] = u;
  } else {
    ((float4*)(h + (size_t)t * DIMC))[tid] = o;
  }
}

// ============ logits: bf16, 256x128 tile, BK=32, dbuf 48KB, 8 waves, 2 blk/CU ============
// counted-vmcnt, rb-fastest XCD-partitioned swizzle (R10-proven; unchanged).
__global__ __launch_bounds__(512, 4) void k_logits(
    const u16* __restrict__ wsb, int offA, int offB,
    const int* __restrict__ pcnt,
    const int* __restrict__ exit_idx,
    float* __restrict__ out)
{
  const int x = blockIdx.x & 7, g = blockIdx.x >> 3;   // grid 4096 = 8 x 512
  const int rb = g & 15;
  const int cb = x * 32 + (g >> 4);                    // 0..255
  if (cb >= VOC / 128) return;                         // 250 real cb
  const int cnt = *pcnt;
  if (rb * 256 >= cnt) return;
  const int n0 = cb * 128;

  __shared__ u16 S[2][12288];          // [A(16 subtiles) | B(8 subtiles)] x 512u16; 48KB
  const int tid = threadIdx.x, w = tid >> 6, l = tid & 63;
  const int lr16 = l & 15, hi = l >> 4;

  int goff[3], loff[3];
#pragma unroll
  for (int q = 0; q < 3; ++q) {
    const int bi = w * 3 + q;          // 24 subtiles: A 0..15, B 16..23
    if (bi < 16) {
      goff[q] = offA + (rb * 256 + bi * 16 + lr16) * DIMC + hi * 8;
      loff[q] = bi * 512;
    } else {
      const int j = bi - 16;
      goff[q] = offB + (n0 + j * 16 + lr16) * DIMC + hi * 8;
      loff[q] = 8192 + j * 512;
    }
  }

  const int wr = w >> 1, wc = w & 1;   // 4M x 2N wave grid, wave tile 64x64
  f32x4 acc[4][4];
#pragma unroll
  for (int mi = 0; mi < 4; ++mi)
#pragma unroll
    for (int ni = 0; ni < 4; ++ni) acc[mi][ni] = (f32x4){0.f, 0.f, 0.f, 0.f};

  auto STAGE = [&](int buf, int kt) {
#pragma unroll
    for (int q = 0; q < 3; ++q)
      gll16(wsb + (size_t)(goff[q] + kt * 32), (void*)&S[buf][loff[q]]);
  };

  STAGE(0, 0);
  STAGE(1, 1);
  const int NT = DIMC / 32;            // 32
  for (int kt = 0; kt < NT; ++kt) {
    const int cur = kt & 1;
    if (kt + 1 < NT) asm volatile("s_waitcnt vmcnt(3)" ::: "memory");
    else             asm volatile("s_waitcnt vmcnt(0)" ::: "memory");
    __builtin_amdgcn_s_barrier();
    bf16x8 aF[4], bF[4];
#pragma unroll
    for (int mi = 0; mi < 4; ++mi)
      aF[mi] = *(const bf16x8*)&S[cur][(wr * 4 + mi) * 512 + l * 8];
#pragma unroll
    for (int ni = 0; ni < 4; ++ni)
      bF[ni] = *(const bf16x8*)&S[cur][8192 + (wc * 4 + ni) * 512 + l * 8];
    __builtin_amdgcn_s_setprio(1);
#pragma unroll
    for (int mi = 0; mi < 4; ++mi)
#pragma unroll
      for (int ni = 0; ni < 4; ++ni)
        acc[mi][ni] = __builtin_amdgcn_mfma_f32_16x16x32_bf16(aF[mi], bF[ni], acc[mi][ni], 0, 0, 0);
    __builtin_amdgcn_s_setprio(0);
    asm volatile("s_waitcnt lgkmcnt(0)" ::: "memory");
    __builtin_amdgcn_s_barrier();
    if (kt + 2 < NT) STAGE(cur, kt + 2);
  }

  const int mvalid = cnt - rb * 256;
#pragma unroll
  for (int mi = 0; mi < 4; ++mi)
#pragma unroll
    for (int r = 0; r < 4; ++r) {
      const int mrow = wr * 64 + mi * 16 + hi * 4 + r;
      if (mrow < mvalid) {
        const int tok = exit_idx[rb * 256 + mrow];
        float* orow = out + (size_t)tok * VOC + n0 + wc * 64 + lr16;
#pragma unroll
        for (int ni = 0; ni < 4; ++ni)
          __builtin_nontemporal_store(acc[mi][ni][r], &orow[ni * 16]);
      }
    }
}

// ---------------- host ----------------
extern "C" void kernel_launch(void* const* d_in, const int* in_sizes, int n_in,
                              void* d_out, int out_size, void* d_ws, size_t ws_size,
                              hipStream_t stream)
{
  const int*   x    = (const int*)d_in[0];
  const float* emb  = (const float*)d_in[1];
  const float* ln_g = (const float*)d_in[2];
  const float* ln_b = (const float*)d_in[3];
  const float* W1   = (const float*)d_in[4];
  const float* b1   = (const float*)d_in[5];
  const float* W2   = (const float*)d_in[6];
  const float* b2   = (const float*)d_in[7];
  const float* Wout = (const float*)d_in[8];
  float* out = (float*)d_out;

  char* p = (char*)d_ws;
  size_t off = 0;
  auto alloc = [&](size_t bytes) -> void* {
    void* r = p + off;
    off += (bytes + 255) & ~(size_t)255;
    return r;
  };
  u16* wsb = (u16*)d_ws;
  float* h    = (float*)alloc((size_t)TK * DIMC * 4);
  float* pbuf = (float*)alloc((size_t)2 * TK * DIMC * 4);   // gemm2 partials; hn planes alias
  u16* hn1 = (u16*)pbuf;
  u16* hn2 = hn1 + (size_t)TK * DIMC;
  u16* act1 = (u16*)alloc((size_t)2 * TK * DFFC * 2);       // act1 | act2 contiguous
  u16* act2 = act1 + (size_t)TK * DFFC;
  u16* Woutb = (u16*)alloc((size_t)VOC * DIMC * 2);
  u16* Wt = (u16*)alloc((size_t)2 * DFFC * DIMC * 2);       // shared by W1t / W2t (sequential)
  u16* hexit = (u16*)alloc((size_t)TK * DIMC * 2);
  int* exit_idx = (int*)alloc((size_t)TK * 4);
  int* surv_a   = (int*)alloc((size_t)TK * 4);
  int* surv_b   = (int*)alloc((size_t)TK * 4);
  int* cnts     = (int*)alloc(64 * 4);
  // cnts[0..2]=exit counts; cnts[4..6]=survivor counts; cnts[12]=TK

  const int offHn  = (int)(hn1  - wsb);
  const int offAct = (int)(act1 - wsb);
  const int offWob = (int)(Woutb- wsb);
  const int offWt  = (int)(Wt   - wsb);
  const int offHex = (int)(hexit- wsb);
  const int pstrHn  = TK * DIMC;
  const int pstrAct = TK * DFFC;
  const int pstrW   = DFFC * DIMC;

  k_init<<<TK, 256, 0, stream>>>(x, emb, h, surv_a, cnts);
  k_cvtb<<<2048, 256, 0, stream>>>(Wout, Woutb, VOC * DIMC / 4);
  int* surv_in  = surv_a;
  int* surv_out = surv_b;
  for (int i = 0; i < NL; ++i) {
    const int* pM = (i == 0) ? (cnts + 12) : (cnts + 4 + (i - 1));
    k_ln<<<TK, 256, 0, stream>>>(h, surv_in, pM, ln_g + i * DIMC, ln_b + i * DIMC, hn1, hn2);
    k_splitw<<<dim3(DIMC / 64, DFFC / 64), 256, 0, stream>>>(
        W1 + (size_t)i * DIMC * DFFC, DIMC, DFFC, Wt, Wt + (size_t)DFFC * DIMC);
    // gemm1: grid 1024 = 8 XCD x (32 rb x 4 cbl)
    k_mlp<0, DIMC><<<1024, 256, 0, stream>>>(
        wsb, offHn, pstrHn, offWt, pstrW, pM, DIMC,
        b1 + (size_t)i * DFFC, act1, act2, nullptr, 1.f / 4096.f);
    k_splitw<<<dim3(DFFC / 64, DIMC / 64), 256, 0, stream>>>(
        W2 + (size_t)i * DFFC * DIMC, DFFC, DIMC, Wt, Wt + (size_t)DIMC * DFFC);
    // gemm2: grid 512 = 8 XCD x (32 rb x 2 cz), split-K2
    k_mlp<1, DFFC><<<512, 256, 0, stream>>>(
        wsb, offAct, pstrAct, offWt, pstrW, pM, DFFC / 2,
        nullptr, nullptr, nullptr, pbuf, 1.f / 16384.f);
    k_decide<<<TK, 256, 0, stream>>>(h, pbuf, b2 + (size_t)i * DIMC,
        surv_in, surv_out, pM, cnts, exit_idx, hexit, i);
    // logits: grid 4096 = 8 XCD x (16 rb x 32 cbl), cb>=250 idle
    k_logits<<<4096, 512, 0, stream>>>(wsb, offHex, offWob, cnts + i, exit_idx, out);
    int* tmp = surv_in; surv_in = surv_out; surv_out = tmp;
  }
}

// Round 12
// 1366.952 us; speedup vs baseline: 1.5729x; 1.0348x over previous
//
#include <hip/hip_runtime.h>
#include <hip/hip_bf16.h>
#include <stdint.h>

constexpr int TK   = 4096;   // B*S tokens
constexpr int DIMC = 1024;
constexpr int DFFC = 4096;
constexpr int VOC  = 32000;
constexpr int NL   = 3;

typedef __attribute__((ext_vector_type(8))) short bf16x8;
typedef __attribute__((ext_vector_type(8))) _Float16 half8;
typedef __attribute__((ext_vector_type(4))) float f32x4;
using u16 = unsigned short;

__device__ __forceinline__ u16 f2bf(float f) {
  unsigned int u = __float_as_uint(f);
  u += 0x7FFF + ((u >> 16) & 1);           // RNE; inputs finite
  return (u16)(u >> 16);
}

__device__ __forceinline__ void split16(float v, u16& hi, u16& lo) {
  _Float16 a = (_Float16)v;
  _Float16 b = (_Float16)(v - (float)a);
  hi = __builtin_bit_cast(u16, a);
  lo = __builtin_bit_cast(u16, b);
}

__device__ __forceinline__ float gelu_f(float x) {
  float x3 = x * x * x;
  return 0.5f * x * (1.0f + tanhf(0.7978845608028654f * (x + 0.044715f * x3)));
}

// async global->LDS, 16B/lane; LDS dest = wave-uniform base (+lane*16 in HW)
__device__ __forceinline__ void gll16(const void* g, void* l) {
  __builtin_amdgcn_global_load_lds(
      (const __attribute__((address_space(1))) unsigned int*)g,
      (__attribute__((address_space(3))) unsigned int*)l, 16, 0, 0);
}

// ---------------- init ----------------
__global__ __launch_bounds__(256) void k_init(const int* __restrict__ x,
    const float* __restrict__ emb, float* __restrict__ h,
    int* __restrict__ surv, int* __restrict__ cnts) {
  const int t = blockIdx.x, tid = threadIdx.x;
  if (t == 0 && tid < 16) cnts[tid] = (tid == 12) ? TK : 0;
  if (tid == 0) surv[t] = t;
  const int tok = x[t];
  ((float4*)(h + (size_t)t * DIMC))[tid] =
      ((const float4*)(emb + (size_t)tok * DIMC))[tid];
}

// ---------------- layernorm -> 2 fp16 planes (x16 scale) ----------------
__global__ __launch_bounds__(256) void k_ln(const float* __restrict__ h,
    const int* __restrict__ surv, const int* __restrict__ pM,
    const float* __restrict__ g, const float* __restrict__ b,
    u16* __restrict__ hn1, u16* __restrict__ hn2) {
  const int bidx = blockIdx.x;
  if (bidx >= *pM) return;
  const int t = surv[bidx];
  const int tid = threadIdx.x;
  const int lane = tid & 63, wid = tid >> 6;
  __shared__ float sm[4];
  float4 v = ((const float4*)(h + (size_t)t * DIMC))[tid];
  float s = v.x + v.y + v.z + v.w;
#pragma unroll
  for (int o = 32; o; o >>= 1) s += __shfl_down(s, o);
  if (lane == 0) sm[wid] = s;
  __syncthreads();
  const float mean = (sm[0] + sm[1] + sm[2] + sm[3]) * (1.0f / DIMC);
  __syncthreads();
  float4 d;
  d.x = v.x - mean; d.y = v.y - mean; d.z = v.z - mean; d.w = v.w - mean;
  float q = d.x * d.x + d.y * d.y + d.z * d.z + d.w * d.w;
#pragma unroll
  for (int o = 32; o; o >>= 1) q += __shfl_down(q, o);
  if (lane == 0) sm[wid] = q;
  __syncthreads();
  const float var = (sm[0] + sm[1] + sm[2] + sm[3]) * (1.0f / DIMC);
  const float rstd = 1.0f / sqrtf(var + 1e-5f);
  float4 gg = ((const float4*)g)[tid];
  float4 bb = ((const float4*)b)[tid];
  float o4[4];
  o4[0] = (d.x * rstd * gg.x + bb.x) * 16.f;
  o4[1] = (d.y * rstd * gg.y + bb.y) * 16.f;
  o4[2] = (d.z * rstd * gg.z + bb.z) * 16.f;
  o4[3] = (d.w * rstd * gg.w + bb.w) * 16.f;
  ushort4 u1, u2;
  split16(o4[0], u1.x, u2.x); split16(o4[1], u1.y, u2.y);
  split16(o4[2], u1.z, u2.z); split16(o4[3], u1.w, u2.w);
  ((ushort4*)(hn1 + (size_t)bidx * DIMC))[tid] = u1;
  ((ushort4*)(hn2 + (size_t)bidx * DIMC))[tid] = u2;
}

// ---------------- weight transpose + fp16 2-split (x256 scale), 64x64, ushort4 writes ----
__global__ __launch_bounds__(256) void k_splitw(const float* __restrict__ W,
    int K, int N, u16* __restrict__ O1, u16* __restrict__ O2) {
  __shared__ float t[64][65];
  const int bk = blockIdx.x * 64, bn = blockIdx.y * 64;
  const int lx = threadIdx.x & 63, ly = threadIdx.x >> 6;
#pragma unroll
  for (int i = 0; i < 64; i += 4)
    t[ly + i][lx] = W[(size_t)(bk + ly + i) * N + bn + lx];
  __syncthreads();
  const int n4 = threadIdx.x >> 4;
  const int kq = (threadIdx.x & 15) * 4;
#pragma unroll
  for (int j = 0; j < 4; ++j) {
    const int n = j * 16 + n4;
    ushort4 h1, h2;
    {
      float v0 = t[kq + 0][n] * 256.f, v1 = t[kq + 1][n] * 256.f;
      float v2 = t[kq + 2][n] * 256.f, v3 = t[kq + 3][n] * 256.f;
      split16(v0, h1.x, h2.x); split16(v1, h1.y, h2.y);
      split16(v2, h1.z, h2.z); split16(v3, h1.w, h2.w);
    }
    const size_t o = (size_t)(bn + n) * K + bk + kq;
    *(ushort4*)&O1[o] = h1;
    *(ushort4*)&O2[o] = h2;
  }
}

// ---------------- f32 -> bf16 bulk convert (Wout, once per call) ----------------
__global__ __launch_bounds__(256) void k_cvtb(const float* __restrict__ in,
    u16* __restrict__ o, int n4) {
  int i = blockIdx.x * blockDim.x + threadIdx.x;
  const int stride = gridDim.x * blockDim.x;
  for (; i < n4; i += stride) {
    float4 v = ((const float4*)in)[i];
    ushort4 u;
    u.x = f2bf(v.x); u.y = f2bf(v.y); u.z = f2bf(v.z); u.w = f2bf(v.w);
    ((ushort4*)o)[i] = u;
  }
}

// ============ gemm1: 256x256 tile, 8 waves (128x64), BK=32, counted-vmcnt dbuf 128KB ============
// C ~= (A1+A2)(B1+B2)^T 3-term;  act = split64(gelu(C/4096 + b1))
__global__ __launch_bounds__(512, 1) void k_mlp1(
    const u16* __restrict__ wsb,
    int offA, int pstrA,            // hn planes [TK][DIMC]
    int offB, int pstrB,            // W1t planes [DFFC][DIMC]
    const int* __restrict__ pM,
    const float* __restrict__ bias,
    u16* __restrict__ O1, u16* __restrict__ O2)
{
  const int x = blockIdx.x & 7, g = blockIdx.x >> 3;   // grid 256 = 8 x 32
  const int rb = g & 15;                               // rb-fastest
  const int cb = x * 2 + (g >> 4);                     // 2 cb per XCD (B L2-resident)
  const int M = *pM;
  if (rb * 256 >= M) return;
  const int n0 = cb * 256;

  __shared__ u16 S[2][32768];     // dbuf x [A1(16)|A2(16)|B1(16)|B2(16)] subtiles of 512u16
  const int tid = threadIdx.x, w = tid >> 6, l = tid & 63;
  const int lr16 = l & 15, hi = l >> 4;

  // staging: wave w owns subtiles w*8..w*8+7
  int goff[8];
#pragma unroll
  for (int q = 0; q < 8; ++q) {
    const int bi = w * 8 + q;
    const int side = bi >> 5;                  // 0=A, 1=B
    const int pl = (bi >> 4) & 1;
    const int j = bi & 15;
    const int row = (side ? n0 : rb * 256) + j * 16 + lr16;
    const int base = side ? (offB + pl * pstrB) : (offA + pl * pstrA);
    goff[q] = base + row * DIMC + hi * 8;
  }

  const int wr = w >> 2, wc = w & 3;           // 2M x 4N wave grid, wave tile 128x64
  f32x4 acc[8][4];
#pragma unroll
  for (int mi = 0; mi < 8; ++mi)
#pragma unroll
    for (int ni = 0; ni < 4; ++ni) acc[mi][ni] = (f32x4){0.f, 0.f, 0.f, 0.f};

  auto STAGE = [&](int buf, int kt) {
#pragma unroll
    for (int q = 0; q < 8; ++q)
      gll16(wsb + (size_t)(goff[q] + kt * 32), (void*)&S[buf][(w * 8 + q) * 512]);
  };

  STAGE(0, 0);
  STAGE(1, 1);
  const int NT = DIMC / 32;                    // 32
  for (int kt = 0; kt < NT; ++kt) {
    const int cur = kt & 1;
    if (kt + 1 < NT) asm volatile("s_waitcnt vmcnt(8)" ::: "memory");
    else             asm volatile("s_waitcnt vmcnt(0)" ::: "memory");
    __builtin_amdgcn_s_barrier();
    half8 b1v[4], b2v[4];
#pragma unroll
    for (int ni = 0; ni < 4; ++ni) {
      const int sub = (32 + wc * 4 + ni) * 512 + l * 8;
      b1v[ni] = *(const half8*)&S[cur][sub];
      b2v[ni] = *(const half8*)&S[cur][sub + 8192];
    }
#pragma unroll
    for (int mh = 0; mh < 2; ++mh) {
      half8 a1v[4], a2v[4];
#pragma unroll
      for (int i = 0; i < 4; ++i) {
        const int sub = (wr * 8 + mh * 4 + i) * 512 + l * 8;
        a1v[i] = *(const half8*)&S[cur][sub];
        a2v[i] = *(const half8*)&S[cur][sub + 8192];
      }
      __builtin_amdgcn_s_setprio(1);
#pragma unroll
      for (int i = 0; i < 4; ++i)
#pragma unroll
        for (int ni = 0; ni < 4; ++ni) {
          f32x4 c = acc[mh * 4 + i][ni];
          c = __builtin_amdgcn_mfma_f32_16x16x32_f16(a2v[i], b1v[ni], c, 0, 0, 0);
          c = __builtin_amdgcn_mfma_f32_16x16x32_f16(a1v[i], b2v[ni], c, 0, 0, 0);
          c = __builtin_amdgcn_mfma_f32_16x16x32_f16(a1v[i], b1v[ni], c, 0, 0, 0);
          acc[mh * 4 + i][ni] = c;
        }
      __builtin_amdgcn_s_setprio(0);
    }
    asm volatile("s_waitcnt lgkmcnt(0)" ::: "memory");
    __builtin_amdgcn_s_barrier();
    if (kt + 2 < NT) STAGE(cur, kt + 2);
  }

#pragma unroll
  for (int mi = 0; mi < 8; ++mi)
#pragma unroll
    for (int ni = 0; ni < 4; ++ni) {
      const int n = n0 + wc * 64 + ni * 16 + lr16;
#pragma unroll
      for (int r = 0; r < 4; ++r) {
        const int m = rb * 256 + wr * 128 + mi * 16 + hi * 4 + r;
        float v = gelu_f(acc[mi][ni][r] * (1.f / 4096.f) + bias[n]) * 64.f;
        u16 h1, h2; split16(v, h1, h2);
        O1[(size_t)m * DFFC + n] = h1;
        O2[(size_t)m * DFFC + n] = h2;
      }
    }
}

// ============ gemm2: 256x128 tile, split-K2, 8 waves (64x64), BK=32, dbuf 96KB ============
// counted-vmcnt.  PO[z-slab] = C/16384
__global__ __launch_bounds__(512, 1) void k_mlp2(
    const u16* __restrict__ wsb,
    int offA, int pstrA,            // act planes [TK][DFFC]
    int offB, int pstrB,            // W2t planes [DIMC][DFFC]
    const int* __restrict__ pM,
    float* __restrict__ PO)
{
  const int x = blockIdx.x & 7, g = blockIdx.x >> 3;   // grid 256 = 8 x 32
  const int rb = g & 15;
  const int cz = x * 2 + (g >> 4);                     // 0..15
  const int cb = cz & 7, z = cz >> 3;
  const int M = *pM;
  if (rb * 256 >= M) return;
  const int n0 = cb * 128;
  const int kz = z * 2048;

  __shared__ u16 S[2][24576];     // dbuf x [A1(16)|A2(16)|B1(8)|B2(8)] subtiles of 512u16
  const int tid = threadIdx.x, w = tid >> 6, l = tid & 63;
  const int lr16 = l & 15, hi = l >> 4;

  int goff[6];
#pragma unroll
  for (int q = 0; q < 6; ++q) {
    const int bi = w * 6 + q;
    int base, row;
    if (bi < 32) {
      const int pl = bi >> 4, j = bi & 15;
      base = offA + pl * pstrA;
      row = rb * 256 + j * 16 + lr16;
    } else {
      const int bb = bi - 32, pl = bb >> 3, j = bb & 7;
      base = offB + pl * pstrB;
      row = n0 + j * 16 + lr16;
    }
    goff[q] = base + row * DFFC + kz + hi * 8;
  }

  const int wr = w >> 1, wc = w & 1;           // 4M x 2N wave grid, wave tile 64x64
  f32x4 acc[4][4];
#pragma unroll
  for (int mi = 0; mi < 4; ++mi)
#pragma unroll
    for (int ni = 0; ni < 4; ++ni) acc[mi][ni] = (f32x4){0.f, 0.f, 0.f, 0.f};

  auto STAGE = [&](int buf, int kt) {
#pragma unroll
    for (int q = 0; q < 6; ++q)
      gll16(wsb + (size_t)(goff[q] + kt * 32), (void*)&S[buf][(w * 6 + q) * 512]);
  };

  STAGE(0, 0);
  STAGE(1, 1);
  const int NT = 2048 / 32;                    // 64
  for (int kt = 0; kt < NT; ++kt) {
    const int cur = kt & 1;
    if (kt + 1 < NT) asm volatile("s_waitcnt vmcnt(6)" ::: "memory");
    else             asm volatile("s_waitcnt vmcnt(0)" ::: "memory");
    __builtin_amdgcn_s_barrier();
    half8 a1v[4], a2v[4], b1v[4], b2v[4];
#pragma unroll
    for (int mi = 0; mi < 4; ++mi) {
      const int sub = (wr * 4 + mi) * 512 + l * 8;
      a1v[mi] = *(const half8*)&S[cur][sub];
      a2v[mi] = *(const half8*)&S[cur][sub + 8192];
    }
#pragma unroll
    for (int ni = 0; ni < 4; ++ni) {
      const int sub = (32 + wc * 4 + ni) * 512 + l * 8;
      b1v[ni] = *(const half8*)&S[cur][sub];
      b2v[ni] = *(const half8*)&S[cur][sub + 4096];
    }
    __builtin_amdgcn_s_setprio(1);
#pragma unroll
    for (int mi = 0; mi < 4; ++mi)
#pragma unroll
      for (int ni = 0; ni < 4; ++ni) {
        f32x4 c = acc[mi][ni];
        c = __builtin_amdgcn_mfma_f32_16x16x32_f16(a2v[mi], b1v[ni], c, 0, 0, 0);
        c = __builtin_amdgcn_mfma_f32_16x16x32_f16(a1v[mi], b2v[ni], c, 0, 0, 0);
        c = __builtin_amdgcn_mfma_f32_16x16x32_f16(a1v[mi], b1v[ni], c, 0, 0, 0);
        acc[mi][ni] = c;
      }
    __builtin_amdgcn_s_setprio(0);
    asm volatile("s_waitcnt lgkmcnt(0)" ::: "memory");
    __builtin_amdgcn_s_barrier();
    if (kt + 2 < NT) STAGE(cur, kt + 2);
  }

#pragma unroll
  for (int mi = 0; mi < 4; ++mi)
#pragma unroll
    for (int ni = 0; ni < 4; ++ni) {
      const int n = n0 + wc * 64 + ni * 16 + lr16;
#pragma unroll
      for (int r = 0; r < 4; ++r) {
        const int m = rb * 256 + wr * 64 + mi * 16 + hi * 4 + r;
        PO[(size_t)(z * TK + m) * DIMC + n] = acc[mi][ni][r] * (1.f / 16384.f);
      }
    }
}

// ---------------- decide: o = h + p0 + p1 + b2; cos; route token ----------------
__global__ __launch_bounds__(256) void k_decide(
    float* __restrict__ h, const float* __restrict__ p,
    const float* __restrict__ bias,
    const int* __restrict__ surv_in, int* __restrict__ surv_out,
    const int* __restrict__ pM, int* __restrict__ cnts,
    int* __restrict__ exit_idx, u16* __restrict__ hexit,
    int stage)
{
  const int bidx = blockIdx.x;
  if (bidx >= *pM) return;
  const int t = surv_in[bidx];
  const int tid = threadIdx.x;
  const int lane = tid & 63, wid = tid >> 6;
  __shared__ float sm[12];
  __shared__ int sif[2];
  float4 a  = ((const float4*)(h + (size_t)t * DIMC))[tid];
  float4 p0 = ((const float4*)(p + (size_t)bidx * DIMC))[tid];
  float4 p1 = ((const float4*)(p + (size_t)(TK + bidx) * DIMC))[tid];
  float4 bb = ((const float4*)bias)[tid];
  float4 o;
  o.x = a.x + p0.x + p1.x + bb.x;
  o.y = a.y + p0.y + p1.y + bb.y;
  o.z = a.z + p0.z + p1.z + bb.z;
  o.w = a.w + p0.w + p1.w + bb.w;
  float hh = a.x * a.x + a.y * a.y + a.z * a.z + a.w * a.w;
  float ho = a.x * o.x + a.y * o.y + a.z * o.z + a.w * o.w;
  float oo = o.x * o.x + o.y * o.y + o.z * o.z + o.w * o.w;
#pragma unroll
  for (int off = 32; off; off >>= 1) {
    hh += __shfl_down(hh, off);
    ho += __shfl_down(ho, off);
    oo += __shfl_down(oo, off);
  }
  if (lane == 0) { sm[wid] = hh; sm[4 + wid] = ho; sm[8 + wid] = oo; }
  __syncthreads();
  if (tid == 0) {
    int take;
    if (stage == NL - 1) take = 1;
    else {
      const float HH = sm[0] + sm[1] + sm[2] + sm[3];
      const float HO = sm[4] + sm[5] + sm[6] + sm[7];
      const float OO = sm[8] + sm[9] + sm[10] + sm[11];
      const float cosv = HO / (sqrtf(HH) * sqrtf(OO) + 1e-8f);
      take = (cosv >= 0.98f) ? 1 : 0;
    }
    int pos;
    if (take) {
      pos = atomicAdd(&cnts[stage], 1);
      exit_idx[pos] = t;
    } else {
      pos = atomicAdd(&cnts[4 + stage], 1);
      surv_out[pos] = t;
    }
    sif[0] = take; sif[1] = pos;
  }
  __syncthreads();
  if (sif[0]) {
    u16* dst = hexit + (size_t)sif[1] * DIMC;
    ushort4 u;
    u.x = f2bf(o.x); u.y = f2bf(o.y); u.z = f2bf(o.z); u.w = f2bf(o.w);
    ((ushort4*)dst)[tid] = u;
  } else {
    ((float4*)(h + (size_t)t * DIMC))[tid] = o;
  }
}

// ============ logits: bf16, 256x128 tile, BK=32, dbuf 48KB, 8 waves, 2 blk/CU ============
// counted-vmcnt, rb-fastest XCD-partitioned swizzle (R10-proven; unchanged).
__global__ __launch_bounds__(512, 4) void k_logits(
    const u16* __restrict__ wsb, int offA, int offB,
    const int* __restrict__ pcnt,
    const int* __restrict__ exit_idx,
    float* __restrict__ out)
{
  const int x = blockIdx.x & 7, g = blockIdx.x >> 3;   // grid 4096 = 8 x 512
  const int rb = g & 15;
  const int cb = x * 32 + (g >> 4);                    // 0..255
  if (cb >= VOC / 128) return;                         // 250 real cb
  const int cnt = *pcnt;
  if (rb * 256 >= cnt) return;
  const int n0 = cb * 128;

  __shared__ u16 S[2][12288];          // [A(16 subtiles) | B(8 subtiles)] x 512u16; 48KB
  const int tid = threadIdx.x, w = tid >> 6, l = tid & 63;
  const int lr16 = l & 15, hi = l >> 4;

  int goff[3], loff[3];
#pragma unroll
  for (int q = 0; q < 3; ++q) {
    const int bi = w * 3 + q;          // 24 subtiles: A 0..15, B 16..23
    if (bi < 16) {
      goff[q] = offA + (rb * 256 + bi * 16 + lr16) * DIMC + hi * 8;
      loff[q] = bi * 512;
    } else {
      const int j = bi - 16;
      goff[q] = offB + (n0 + j * 16 + lr16) * DIMC + hi * 8;
      loff[q] = 8192 + j * 512;
    }
  }

  const int wr = w >> 1, wc = w & 1;   // 4M x 2N wave grid, wave tile 64x64
  f32x4 acc[4][4];
#pragma unroll
  for (int mi = 0; mi < 4; ++mi)
#pragma unroll
    for (int ni = 0; ni < 4; ++ni) acc[mi][ni] = (f32x4){0.f, 0.f, 0.f, 0.f};

  auto STAGE = [&](int buf, int kt) {
#pragma unroll
    for (int q = 0; q < 3; ++q)
      gll16(wsb + (size_t)(goff[q] + kt * 32), (void*)&S[buf][loff[q]]);
  };

  STAGE(0, 0);
  STAGE(1, 1);
  const int NT = DIMC / 32;            // 32
  for (int kt = 0; kt < NT; ++kt) {
    const int cur = kt & 1;
    if (kt + 1 < NT) asm volatile("s_waitcnt vmcnt(3)" ::: "memory");
    else             asm volatile("s_waitcnt vmcnt(0)" ::: "memory");
    __builtin_amdgcn_s_barrier();
    bf16x8 aF[4], bF[4];
#pragma unroll
    for (int mi = 0; mi < 4; ++mi)
      aF[mi] = *(const bf16x8*)&S[cur][(wr * 4 + mi) * 512 + l * 8];
#pragma unroll
    for (int ni = 0; ni < 4; ++ni)
      bF[ni] = *(const bf16x8*)&S[cur][8192 + (wc * 4 + ni) * 512 + l * 8];
    __builtin_amdgcn_s_setprio(1);
#pragma unroll
    for (int mi = 0; mi < 4; ++mi)
#pragma unroll
      for (int ni = 0; ni < 4; ++ni)
        acc[mi][ni] = __builtin_amdgcn_mfma_f32_16x16x32_bf16(aF[mi], bF[ni], acc[mi][ni], 0, 0, 0);
    __builtin_amdgcn_s_setprio(0);
    asm volatile("s_waitcnt lgkmcnt(0)" ::: "memory");
    __builtin_amdgcn_s_barrier();
    if (kt + 2 < NT) STAGE(cur, kt + 2);
  }

  const int mvalid = cnt - rb * 256;
#pragma unroll
  for (int mi = 0; mi < 4; ++mi)
#pragma unroll
    for (int r = 0; r < 4; ++r) {
      const int mrow = wr * 64 + mi * 16 + hi * 4 + r;
      if (mrow < mvalid) {
        const int tok = exit_idx[rb * 256 + mrow];
        float* orow = out + (size_t)tok * VOC + n0 + wc * 64 + lr16;
#pragma unroll
        for (int ni = 0; ni < 4; ++ni)
          __builtin_nontemporal_store(acc[mi][ni][r], &orow[ni * 16]);
      }
    }
}

// ---------------- host ----------------
extern "C" void kernel_launch(void* const* d_in, const int* in_sizes, int n_in,
                              void* d_out, int out_size, void* d_ws, size_t ws_size,
                              hipStream_t stream)
{
  const int*   x    = (const int*)d_in[0];
  const float* emb  = (const float*)d_in[1];
  const float* ln_g = (const float*)d_in[2];
  const float* ln_b = (const float*)d_in[3];
  const float* W1   = (const float*)d_in[4];
  const float* b1   = (const float*)d_in[5];
  const float* W2   = (const float*)d_in[6];
  const float* b2   = (const float*)d_in[7];
  const float* Wout = (const float*)d_in[8];
  float* out = (float*)d_out;

  char* p = (char*)d_ws;
  size_t off = 0;
  auto alloc = [&](size_t bytes) -> void* {
    void* r = p + off;
    off += (bytes + 255) & ~(size_t)255;
    return r;
  };
  u16* wsb = (u16*)d_ws;
  float* h    = (float*)alloc((size_t)TK * DIMC * 4);
  float* pbuf = (float*)alloc((size_t)2 * TK * DIMC * 4);   // gemm2 partials; hn planes alias
  u16* hn1 = (u16*)pbuf;
  u16* hn2 = hn1 + (size_t)TK * DIMC;
  u16* act1 = (u16*)alloc((size_t)2 * TK * DFFC * 2);       // act1 | act2 contiguous
  u16* act2 = act1 + (size_t)TK * DFFC;
  u16* Woutb = (u16*)alloc((size_t)VOC * DIMC * 2);
  u16* Wt = (u16*)alloc((size_t)2 * DFFC * DIMC * 2);       // shared by W1t / W2t (sequential)
  u16* hexit = (u16*)alloc((size_t)TK * DIMC * 2);
  int* exit_idx = (int*)alloc((size_t)TK * 4);
  int* surv_a   = (int*)alloc((size_t)TK * 4);
  int* surv_b   = (int*)alloc((size_t)TK * 4);
  int* cnts     = (int*)alloc(64 * 4);
  // cnts[0..2]=exit counts; cnts[4..6]=survivor counts; cnts[12]=TK

  const int offHn  = (int)(hn1  - wsb);
  const int offAct = (int)(act1 - wsb);
  const int offWob = (int)(Woutb- wsb);
  const int offWt  = (int)(Wt   - wsb);
  const int offHex = (int)(hexit- wsb);
  const int pstrHn  = TK * DIMC;
  const int pstrAct = TK * DFFC;
  const int pstrW   = DFFC * DIMC;

  k_init<<<TK, 256, 0, stream>>>(x, emb, h, surv_a, cnts);
  k_cvtb<<<2048, 256, 0, stream>>>(Wout, Woutb, VOC * DIMC / 4);
  int* surv_in  = surv_a;
  int* surv_out = surv_b;
  for (int i = 0; i < NL; ++i) {
    const int* pM = (i == 0) ? (cnts + 12) : (cnts + 4 + (i - 1));
    k_ln<<<TK, 256, 0, stream>>>(h, surv_in, pM, ln_g + i * DIMC, ln_b + i * DIMC, hn1, hn2);
    k_splitw<<<dim3(DIMC / 64, DFFC / 64), 256, 0, stream>>>(
        W1 + (size_t)i * DIMC * DFFC, DIMC, DFFC, Wt, Wt + (size_t)DFFC * DIMC);
    // gemm1: grid 256 = 8 XCD x (16 rb x 2 cbl)
    k_mlp1<<<256, 512, 0, stream>>>(
        wsb, offHn, pstrHn, offWt, pstrW, pM, b1 + (size_t)i * DFFC, act1, act2);
    k_splitw<<<dim3(DFFC / 64, DIMC / 64), 256, 0, stream>>>(
        W2 + (size_t)i * DFFC * DIMC, DFFC, DIMC, Wt, Wt + (size_t)DIMC * DFFC);
    // gemm2: grid 256 = 8 XCD x (16 rb x 2 cz), split-K2
    k_mlp2<<<256, 512, 0, stream>>>(
        wsb, offAct, pstrAct, offWt, pstrW, pM, pbuf);
    k_decide<<<TK, 256, 0, stream>>>(h, pbuf, b2 + (size_t)i * DIMC,
        surv_in, surv_out, pM, cnts, exit_idx, hexit, i);
    // logits: grid 4096 = 8 XCD x (16 rb x 32 cbl), cb>=250 idle
    k_logits<<<4096, 512, 0, stream>>>(wsb, offHex, offWob, cnts + i, exit_idx, out);
    int* tmp = surv_in; surv_in = surv_out; surv_out = tmp;
  }
}